// Round 1
// baseline (661.424 us; speedup 1.0000x reference)
//
#include <hip/hip_runtime.h>
#include <hip/hip_bf16.h>
#include <cstdint>

// Problem constants
#define B_ 2
#define L_ 2048
#define E_ 1024
#define H_ 16
#define D_ 64
#define N3_ 3072
#define NCHUNK 32
#define CHUNK 64

// ---------------------------------------------------------------------------
// Kernel A: qkv = x @ qkv_w.T + qkv_b  (M=4096, N=3072, K=1024), fp32 tiled.
// Epilogue: scatter to Q/K/V in (b,h,l,d) layout, phi(x)=relu(x)+1e-6 on q,k.
// Tile 64x64, BK=16, 256 threads, 4x4 per thread.
// ---------------------------------------------------------------------------
__global__ __launch_bounds__(256) void k_gemm_qkv(
    const float* __restrict__ X, const float* __restrict__ W,
    const float* __restrict__ bias, float* __restrict__ Qf,
    float* __restrict__ Kf, float* __restrict__ Vf) {
  __shared__ float AsT[16][68];  // [k][m], padded
  __shared__ float WsT[16][68];  // [k][n]
  const int tid = threadIdx.x;
  const int tx = tid & 15, ty = tid >> 4;
  const int n0 = blockIdx.x * 64;  // N block (3072)
  const int m0 = blockIdx.y * 64;  // M block (4096)
  const int lrow = tid >> 2;       // 0..63
  const int lk4 = (tid & 3) * 4;   // 0,4,8,12
  float acc[4][4] = {};
  for (int k0 = 0; k0 < 1024; k0 += 16) {
    float4 av = *reinterpret_cast<const float4*>(&X[(size_t)(m0 + lrow) * 1024 + k0 + lk4]);
    float4 wv = *reinterpret_cast<const float4*>(&W[(size_t)(n0 + lrow) * 1024 + k0 + lk4]);
    __syncthreads();
    AsT[lk4 + 0][lrow] = av.x; AsT[lk4 + 1][lrow] = av.y;
    AsT[lk4 + 2][lrow] = av.z; AsT[lk4 + 3][lrow] = av.w;
    WsT[lk4 + 0][lrow] = wv.x; WsT[lk4 + 1][lrow] = wv.y;
    WsT[lk4 + 2][lrow] = wv.z; WsT[lk4 + 3][lrow] = wv.w;
    __syncthreads();
#pragma unroll
    for (int kk = 0; kk < 16; ++kk) {
      float a[4], w[4];
#pragma unroll
      for (int i = 0; i < 4; ++i) a[i] = AsT[kk][ty * 4 + i];
#pragma unroll
      for (int j = 0; j < 4; ++j) w[j] = WsT[kk][tx * 4 + j];
#pragma unroll
      for (int i = 0; i < 4; ++i)
#pragma unroll
        for (int j = 0; j < 4; ++j) acc[i][j] += a[i] * w[j];
    }
  }
#pragma unroll
  for (int i = 0; i < 4; ++i) {
    const int n = m0 + ty * 4 + i;  // row in 4096
    const int b = n >> 11, l = n & 2047;
#pragma unroll
    for (int j = 0; j < 4; ++j) {
      const int m = n0 + tx * 4 + j;  // col in 3072
      float val = acc[i][j] + bias[m];
      const int t = m >> 10, hd = m & 1023;
      const int h = hd >> 6, d = hd & 63;
      const size_t dst = (((size_t)(b * 16 + h)) * 2048 + l) * 64 + d;
      if (t == 0)      Qf[dst] = fmaxf(val, 0.f) + 1e-6f;
      else if (t == 1) Kf[dst] = fmaxf(val, 0.f) + 1e-6f;
      else             Vf[dst] = val;
    }
  }
}

// ---------------------------------------------------------------------------
// Kernel B: per-(b,h,chunk) local KV outer-product sum (64x64) and k-sum (64).
// grid = B*H*NCHUNK = 1024 blocks of 256 threads.
// ---------------------------------------------------------------------------
__global__ __launch_bounds__(256) void k_chunk_sums(
    const float* __restrict__ Kf, const float* __restrict__ Vf,
    float* __restrict__ kvsum, float* __restrict__ zsum) {
  const int bh = blockIdx.x >> 5;  // / NCHUNK
  const int c = blockIdx.x & 31;
  __shared__ float Ks[64][64];
  __shared__ float Vs[64][64];
  const int tid = threadIdx.x;
  const size_t base = ((size_t)bh * L_ + (size_t)c * CHUNK) * D_;
  for (int i = tid; i < 1024; i += 256) {
    reinterpret_cast<float4*>(&Ks[0][0])[i] = *reinterpret_cast<const float4*>(&Kf[base + (size_t)i * 4]);
    reinterpret_cast<float4*>(&Vs[0][0])[i] = *reinterpret_cast<const float4*>(&Vf[base + (size_t)i * 4]);
  }
  __syncthreads();
  const int d = tid >> 2;
  const int eb = (tid & 3) * 16;
  float acc[16];
#pragma unroll
  for (int j = 0; j < 16; ++j) acc[j] = 0.f;
  for (int l = 0; l < 64; ++l) {
    const float kd = Ks[l][d];
#pragma unroll
    for (int j = 0; j < 16; ++j) acc[j] += kd * Vs[l][eb + j];
  }
  const size_t ob = (size_t)blockIdx.x * 4096 + (size_t)d * 64 + eb;
#pragma unroll
  for (int j = 0; j < 16; ++j) kvsum[ob + j] = acc[j];
  if (tid < 64) {
    float z = 0.f;
    for (int l = 0; l < 64; ++l) z += Ks[l][tid];
    zsum[(size_t)blockIdx.x * 64 + tid] = z;
  }
}

// ---------------------------------------------------------------------------
// Kernel C: in-place exclusive prefix over the 32 chunks per (b,h).
// grid = B*H = 32 blocks of 256 threads; each thread owns 16 state elements.
// ---------------------------------------------------------------------------
__global__ __launch_bounds__(256) void k_prefix(float* __restrict__ kvsum,
                                                float* __restrict__ zsum) {
  const int bh = blockIdx.x;
  const int tid = threadIdx.x;
  float run[16];
#pragma unroll
  for (int j = 0; j < 16; ++j) run[j] = 0.f;
  for (int c = 0; c < NCHUNK; ++c) {
    float* p = &kvsum[(((size_t)bh) * NCHUNK + c) * 4096 + (size_t)tid * 16];
#pragma unroll
    for (int j = 0; j < 16; ++j) {
      float t = p[j];
      p[j] = run[j];
      run[j] += t;
    }
  }
  if (tid < 64) {
    float rz = 0.f;
    for (int c = 0; c < NCHUNK; ++c) {
      float* pz = &zsum[(((size_t)bh) * NCHUNK + c) * 64 + tid];
      float t = *pz;
      *pz = rz;
      rz += t;
    }
  }
}

// ---------------------------------------------------------------------------
// Kernel D: per-(b,h,chunk) output.
// num_l = q_l @ S_prefix + sum_{j<=l in chunk} (q_l . k_j) v_j
// den_l = q_l . z_prefix + sum_{j<=l in chunk} (q_l . k_j)
// out = num / max(den, 1e-6), written to attn in (b, l, h*64+e) layout.
// 256 threads: thread = (row r in 0..63) x (16-wide e-group of 4).
// ---------------------------------------------------------------------------
__global__ __launch_bounds__(256) void k_chunk_out(
    const float* __restrict__ Qf, const float* __restrict__ Kf,
    const float* __restrict__ Vf, const float* __restrict__ kvsum,
    const float* __restrict__ zsum, float* __restrict__ attn) {
  const int bh = blockIdx.x >> 5;
  const int c = blockIdx.x & 31;
  const int b = bh >> 4, h = bh & 15;
  __shared__ float Qs[64][68];
  __shared__ float Ks[64][68];
  __shared__ float Ssh[64][68];
  __shared__ float zsh[64];
  const int tid = threadIdx.x;
  const size_t qkbase = ((size_t)bh * L_ + (size_t)c * CHUNK) * D_;
  for (int i = tid; i < 1024; i += 256) {
    const int row = i >> 4;
    const int c4 = (i & 15) * 4;
    *reinterpret_cast<float4*>(&Qs[row][c4]) =
        *reinterpret_cast<const float4*>(&Qf[qkbase + (size_t)row * 64 + c4]);
    *reinterpret_cast<float4*>(&Ks[row][c4]) =
        *reinterpret_cast<const float4*>(&Kf[qkbase + (size_t)row * 64 + c4]);
    *reinterpret_cast<float4*>(&Ssh[row][c4]) =
        *reinterpret_cast<const float4*>(&kvsum[(size_t)blockIdx.x * 4096 + (size_t)row * 64 + c4]);
  }
  if (tid < 64) zsh[tid] = zsum[(size_t)blockIdx.x * 64 + tid];
  __syncthreads();
  const int r = tid >> 2;
  const int eb = (tid & 3) * 16;
  float num[16];
#pragma unroll
  for (int j = 0; j < 16; ++j) num[j] = 0.f;
  float den = 0.f;
  // inter-chunk part: q @ S_prefix, q . z_prefix
#pragma unroll 8
  for (int d = 0; d < 64; ++d) {
    const float qd = Qs[r][d];
    den += qd * zsh[d];
#pragma unroll
    for (int j = 0; j < 16; ++j) num[j] += qd * Ssh[d][eb + j];
  }
  // intra-chunk causal part
  const float* vbase = &Vf[qkbase];
  for (int jj = 0; jj <= r; ++jj) {
    float a = 0.f;
#pragma unroll
    for (int d = 0; d < 64; ++d) a += Qs[r][d] * Ks[jj][d];
    den += a;
    const float* vrow = &vbase[(size_t)jj * 64 + eb];
#pragma unroll
    for (int j = 0; j < 16; ++j) num[j] += a * vrow[j];
  }
  den = fmaxf(den, 1e-6f);
  const float inv = 1.f / den;
  const size_t ob = ((size_t)b * L_ + (size_t)c * CHUNK + r) * E_ + (size_t)h * 64 + eb;
#pragma unroll
  for (int j = 0; j < 16; ++j) attn[ob + j] = num[j] * inv;
}

// ---------------------------------------------------------------------------
// Kernel E: out = attn @ out_w.T + out_b (M=4096, N=1024, K=1024), fp32 tiled.
// ---------------------------------------------------------------------------
__global__ __launch_bounds__(256) void k_gemm_out(
    const float* __restrict__ A, const float* __restrict__ W,
    const float* __restrict__ bias, float* __restrict__ O) {
  __shared__ float AsT[16][68];
  __shared__ float WsT[16][68];
  const int tid = threadIdx.x;
  const int tx = tid & 15, ty = tid >> 4;
  const int n0 = blockIdx.x * 64;  // N block (1024)
  const int m0 = blockIdx.y * 64;  // M block (4096)
  const int lrow = tid >> 2;
  const int lk4 = (tid & 3) * 4;
  float acc[4][4] = {};
  for (int k0 = 0; k0 < 1024; k0 += 16) {
    float4 av = *reinterpret_cast<const float4*>(&A[(size_t)(m0 + lrow) * 1024 + k0 + lk4]);
    float4 wv = *reinterpret_cast<const float4*>(&W[(size_t)(n0 + lrow) * 1024 + k0 + lk4]);
    __syncthreads();
    AsT[lk4 + 0][lrow] = av.x; AsT[lk4 + 1][lrow] = av.y;
    AsT[lk4 + 2][lrow] = av.z; AsT[lk4 + 3][lrow] = av.w;
    WsT[lk4 + 0][lrow] = wv.x; WsT[lk4 + 1][lrow] = wv.y;
    WsT[lk4 + 2][lrow] = wv.z; WsT[lk4 + 3][lrow] = wv.w;
    __syncthreads();
#pragma unroll
    for (int kk = 0; kk < 16; ++kk) {
      float a[4], w[4];
#pragma unroll
      for (int i = 0; i < 4; ++i) a[i] = AsT[kk][ty * 4 + i];
#pragma unroll
      for (int j = 0; j < 4; ++j) w[j] = WsT[kk][tx * 4 + j];
#pragma unroll
      for (int i = 0; i < 4; ++i)
#pragma unroll
        for (int j = 0; j < 4; ++j) acc[i][j] += a[i] * w[j];
    }
  }
#pragma unroll
  for (int i = 0; i < 4; ++i) {
    const int n = m0 + ty * 4 + i;
#pragma unroll
    for (int j = 0; j < 4; ++j) {
      const int m = n0 + tx * 4 + j;
      O[(size_t)n * 1024 + m] = acc[i][j] + bias[m];
    }
  }
}

// ---------------------------------------------------------------------------
extern "C" void kernel_launch(void* const* d_in, const int* in_sizes, int n_in,
                              void* d_out, int out_size, void* d_ws, size_t ws_size,
                              hipStream_t stream) {
  const float* x = (const float*)d_in[0];
  const float* qkv_w = (const float*)d_in[1];
  const float* qkv_b = (const float*)d_in[2];
  const float* out_w = (const float*)d_in[3];
  const float* out_b = (const float*)d_in[4];
  float* out = (float*)d_out;

  float* ws = (float*)d_ws;
  const size_t SZ = (size_t)B_ * H_ * L_ * D_;  // 4,194,304
  float* Qf = ws;
  float* Kf = Qf + SZ;
  float* Vf = Kf + SZ;
  float* attn = Vf + SZ;
  float* kvsum = attn + SZ;                                  // B*H*NCHUNK*64*64 = 4,194,304
  float* zsum = kvsum + (size_t)B_ * H_ * NCHUNK * D_ * D_;  // B*H*NCHUNK*64 = 65,536

  dim3 blk(256);
  k_gemm_qkv<<<dim3(N3_ / 64, (B_ * L_) / 64), blk, 0, stream>>>(x, qkv_w, qkv_b, Qf, Kf, Vf);
  k_chunk_sums<<<dim3(B_ * H_ * NCHUNK), blk, 0, stream>>>(Kf, Vf, kvsum, zsum);
  k_prefix<<<dim3(B_ * H_), blk, 0, stream>>>(kvsum, zsum);
  k_chunk_out<<<dim3(B_ * H_ * NCHUNK), blk, 0, stream>>>(Qf, Kf, Vf, kvsum, zsum, attn);
  k_gemm_out<<<dim3(E_ / 64, (B_ * L_) / 64), blk, 0, stream>>>(attn, out_w, out_b, out);
}

// Round 3
// 268.732 us; speedup vs baseline: 2.4613x; 2.4613x over previous
//
#include <hip/hip_runtime.h>
#include <hip/hip_bf16.h>
#include <cstdint>

// Problem constants
#define B_ 2
#define L_ 2048
#define E_ 1024
#define H_ 16
#define D_ 64
#define N3_ 3072
#define NCHUNK 32
#define CHUNK 64

typedef __attribute__((ext_vector_type(8))) short bf16x8;
typedef __attribute__((ext_vector_type(4))) float f32x4;

__device__ __forceinline__ unsigned short f2bf(float f) {
  unsigned u = __float_as_uint(f);
  unsigned r = (u + 0x7fffu + ((u >> 16) & 1u)) >> 16;  // RNE
  return (unsigned short)r;
}

// ---------------------------------------------------------------------------
// fp32 -> bf16 conversion (vectorized, exact-grid)
// ---------------------------------------------------------------------------
__global__ __launch_bounds__(256) void k_cvt_bf16(const float* __restrict__ src,
                                                  unsigned short* __restrict__ dst,
                                                  int n4) {
  const int i = blockIdx.x * 256 + threadIdx.x;
  if (i < n4) {
    float4 v = reinterpret_cast<const float4*>(src)[i];
    ushort4 o;
    o.x = f2bf(v.x); o.y = f2bf(v.y); o.z = f2bf(v.z); o.w = f2bf(v.w);
    reinterpret_cast<ushort4*>(dst)[i] = o;
  }
}

// ---------------------------------------------------------------------------
// bf16 MFMA GEMM, m97 structure: C(M,N) = A(M,K) @ B(N,K)^T
// 128x128 tile, BK=32, 4 waves (each owns 64x64 = 4x4 fragments of 16x16),
// global_load_lds width=16, 2 barriers per K-step.
// EPI==0: QKV epilogue (bias + relu + eps, scatter to (b,h,l,d) fp32 Q/K/V)
// EPI==1: plain epilogue (bias, store fp32 row-major)
// ---------------------------------------------------------------------------
template <int EPI>
__global__ __launch_bounds__(256) void k_mfma_gemm(
    const unsigned short* __restrict__ A,   // (M,K) bf16 row-major
    const unsigned short* __restrict__ Bm,  // (N,K) bf16 row-major
    const float* __restrict__ bias,         // (N)
    float* __restrict__ O,                  // EPI==1 output (M,N) f32
    float* __restrict__ Qf, float* __restrict__ Kf, float* __restrict__ Vf,
    const int K) {
  __shared__ short As[128 * 32];  // linear [row][k], row-major, no pad (global_load_lds)
  __shared__ short Bs[128 * 32];
  const int tid = threadIdx.x;
  const int lane = tid & 63;
  const int wave = tid >> 6;
  const int wr = wave >> 1, wc = wave & 1;  // wave -> 64x64 sub-tile
  const int m0 = blockIdx.y * 128, n0 = blockIdx.x * 128;
  const int srow = tid >> 2;            // staging row 0..63
  const int scol = (tid & 3) << 3;      // staging k-offset 0,8,16,24
  f32x4 acc[4][4];
#pragma unroll
  for (int i = 0; i < 4; ++i)
#pragma unroll
    for (int j = 0; j < 4; ++j) acc[i][j] = (f32x4){0.f, 0.f, 0.f, 0.f};

  const int l15 = lane & 15, l16 = lane >> 4;
  const int aoff0 = (wr * 64 + l15) * 32 + l16 * 8;  // A frag base (elems)
  const int boff0 = (wc * 64 + l15) * 32 + l16 * 8;  // B frag base

  for (int k0 = 0; k0 < K; k0 += 32) {
    const short* gA = (const short*)&A[(size_t)(m0 + srow) * K + k0 + scol];
    const short* gB = (const short*)&Bm[(size_t)(n0 + srow) * K + k0 + scol];
    __builtin_amdgcn_global_load_lds(
        (const __attribute__((address_space(1))) unsigned int*)gA,
        (__attribute__((address_space(3))) unsigned int*)&As[tid * 8], 16, 0, 0);
    __builtin_amdgcn_global_load_lds(
        (const __attribute__((address_space(1))) unsigned int*)(gA + (size_t)64 * K),
        (__attribute__((address_space(3))) unsigned int*)&As[2048 + tid * 8], 16, 0, 0);
    __builtin_amdgcn_global_load_lds(
        (const __attribute__((address_space(1))) unsigned int*)gB,
        (__attribute__((address_space(3))) unsigned int*)&Bs[tid * 8], 16, 0, 0);
    __builtin_amdgcn_global_load_lds(
        (const __attribute__((address_space(1))) unsigned int*)(gB + (size_t)64 * K),
        (__attribute__((address_space(3))) unsigned int*)&Bs[2048 + tid * 8], 16, 0, 0);
    __syncthreads();  // compiler drains vmcnt(0) before s_barrier
    bf16x8 af[4], bfr[4];
#pragma unroll
    for (int f = 0; f < 4; ++f)
      af[f] = *reinterpret_cast<const bf16x8*>(&As[aoff0 + f * 16 * 32]);
#pragma unroll
    for (int f = 0; f < 4; ++f)
      bfr[f] = *reinterpret_cast<const bf16x8*>(&Bs[boff0 + f * 16 * 32]);
#pragma unroll
    for (int m = 0; m < 4; ++m)
#pragma unroll
      for (int n = 0; n < 4; ++n)
        acc[m][n] = __builtin_amdgcn_mfma_f32_16x16x32_bf16(af[m], bfr[n], acc[m][n], 0, 0, 0);
    __syncthreads();  // protect LDS before next stage
  }

  // epilogue: C/D layout col=lane&15, row=(lane>>4)*4+reg  [m89/m91 verified]
  const int rbase = l16 * 4;
#pragma unroll
  for (int m = 0; m < 4; ++m) {
#pragma unroll
    for (int n = 0; n < 4; ++n) {
      const int col = n0 + wc * 64 + n * 16 + l15;
      const float bv = bias[col];
#pragma unroll
      for (int j = 0; j < 4; ++j) {
        const int row = m0 + wr * 64 + m * 16 + rbase + j;
        const float val = acc[m][n][j] + bv;
        if (EPI == 0) {
          const int b = row >> 11, l = row & 2047;
          const int t = col >> 10, hd = col & 1023;
          const int h = hd >> 6, d = hd & 63;
          const size_t dst = (((size_t)(b * 16 + h)) * 2048 + l) * 64 + d;
          if (t == 0)      Qf[dst] = fmaxf(val, 0.f) + 1e-6f;
          else if (t == 1) Kf[dst] = fmaxf(val, 0.f) + 1e-6f;
          else             Vf[dst] = val;
        } else {
          O[(size_t)row * 1024 + col] = val;
        }
      }
    }
  }
}

// ---------------------------------------------------------------------------
// Kernel B: per-(b,h,chunk) local KV outer-product sum (64x64) and k-sum (64).
// ---------------------------------------------------------------------------
__global__ __launch_bounds__(256) void k_chunk_sums(
    const float* __restrict__ Kf, const float* __restrict__ Vf,
    float* __restrict__ kvsum, float* __restrict__ zsum) {
  const int bh = blockIdx.x >> 5;
  const int c = blockIdx.x & 31;
  __shared__ float Ks[64][64];
  __shared__ float Vs[64][64];
  const int tid = threadIdx.x;
  const size_t base = ((size_t)bh * L_ + (size_t)c * CHUNK) * D_;
  for (int i = tid; i < 1024; i += 256) {
    reinterpret_cast<float4*>(&Ks[0][0])[i] = *reinterpret_cast<const float4*>(&Kf[base + (size_t)i * 4]);
    reinterpret_cast<float4*>(&Vs[0][0])[i] = *reinterpret_cast<const float4*>(&Vf[base + (size_t)i * 4]);
  }
  __syncthreads();
  const int d = tid >> 2;
  const int eb = (tid & 3) * 16;
  float acc[16];
#pragma unroll
  for (int j = 0; j < 16; ++j) acc[j] = 0.f;
  for (int l = 0; l < 64; ++l) {
    const float kd = Ks[l][d];
#pragma unroll
    for (int j = 0; j < 16; ++j) acc[j] += kd * Vs[l][eb + j];
  }
  const size_t ob = (size_t)blockIdx.x * 4096 + (size_t)d * 64 + eb;
#pragma unroll
  for (int j = 0; j < 16; ++j) kvsum[ob + j] = acc[j];
  if (tid < 64) {
    float z = 0.f;
    for (int l = 0; l < 64; ++l) z += Ks[l][tid];
    zsum[(size_t)blockIdx.x * 64 + tid] = z;
  }
}

// ---------------------------------------------------------------------------
// Kernel C: in-place exclusive prefix over 32 chunks per (b,h).
// ---------------------------------------------------------------------------
__global__ __launch_bounds__(256) void k_prefix(float* __restrict__ kvsum,
                                                float* __restrict__ zsum) {
  const int bh = blockIdx.x;
  const int tid = threadIdx.x;
  float run[16];
#pragma unroll
  for (int j = 0; j < 16; ++j) run[j] = 0.f;
  for (int c = 0; c < NCHUNK; ++c) {
    float* p = &kvsum[(((size_t)bh) * NCHUNK + c) * 4096 + (size_t)tid * 16];
#pragma unroll
    for (int j = 0; j < 16; ++j) {
      float t = p[j];
      p[j] = run[j];
      run[j] += t;
    }
  }
  if (tid < 64) {
    float rz = 0.f;
    for (int c = 0; c < NCHUNK; ++c) {
      float* pz = &zsum[(((size_t)bh) * NCHUNK + c) * 64 + tid];
      float t = *pz;
      *pz = rz;
      rz += t;
    }
  }
}

// ---------------------------------------------------------------------------
// Kernel D: per-(b,h,chunk) output; writes attn in bf16 (b, l, h*64+e) layout.
// ---------------------------------------------------------------------------
__global__ __launch_bounds__(256) void k_chunk_out(
    const float* __restrict__ Qf, const float* __restrict__ Kf,
    const float* __restrict__ Vf, const float* __restrict__ kvsum,
    const float* __restrict__ zsum, unsigned short* __restrict__ attnb) {
  const int bh = blockIdx.x >> 5;
  const int c = blockIdx.x & 31;
  const int b = bh >> 4, h = bh & 15;
  __shared__ float Qs[64][68];
  __shared__ float Ks[64][68];
  __shared__ float Ssh[64][68];
  __shared__ float zsh[64];
  const int tid = threadIdx.x;
  const size_t qkbase = ((size_t)bh * L_ + (size_t)c * CHUNK) * D_;
  for (int i = tid; i < 1024; i += 256) {
    const int row = i >> 4;
    const int c4 = (i & 15) * 4;
    *reinterpret_cast<float4*>(&Qs[row][c4]) =
        *reinterpret_cast<const float4*>(&Qf[qkbase + (size_t)row * 64 + c4]);
    *reinterpret_cast<float4*>(&Ks[row][c4]) =
        *reinterpret_cast<const float4*>(&Kf[qkbase + (size_t)row * 64 + c4]);
    *reinterpret_cast<float4*>(&Ssh[row][c4]) =
        *reinterpret_cast<const float4*>(&kvsum[(size_t)blockIdx.x * 4096 + (size_t)row * 64 + c4]);
  }
  if (tid < 64) zsh[tid] = zsum[(size_t)blockIdx.x * 64 + tid];
  __syncthreads();
  const int r = tid >> 2;
  const int eb = (tid & 3) * 16;
  float num[16];
#pragma unroll
  for (int j = 0; j < 16; ++j) num[j] = 0.f;
  float den = 0.f;
#pragma unroll 8
  for (int d = 0; d < 64; ++d) {
    const float qd = Qs[r][d];
    den += qd * zsh[d];
#pragma unroll
    for (int j = 0; j < 16; ++j) num[j] += qd * Ssh[d][eb + j];
  }
  const float* vbase = &Vf[qkbase];
  for (int jj = 0; jj <= r; ++jj) {
    float a = 0.f;
#pragma unroll
    for (int d = 0; d < 64; ++d) a += Qs[r][d] * Ks[jj][d];
    den += a;
    const float* vrow = &vbase[(size_t)jj * 64 + eb];
#pragma unroll
    for (int j = 0; j < 16; ++j) num[j] += a * vrow[j];
  }
  den = fmaxf(den, 1e-6f);
  const float inv = 1.f / den;
  const size_t ob = ((size_t)b * L_ + (size_t)c * CHUNK + r) * E_ + (size_t)h * 64 + eb;
#pragma unroll
  for (int q4 = 0; q4 < 4; ++q4) {
    ushort4 o;
    o.x = f2bf(num[q4 * 4 + 0] * inv);
    o.y = f2bf(num[q4 * 4 + 1] * inv);
    o.z = f2bf(num[q4 * 4 + 2] * inv);
    o.w = f2bf(num[q4 * 4 + 3] * inv);
    *reinterpret_cast<ushort4*>(&attnb[ob + q4 * 4]) = o;
  }
}

// ---------------------------------------------------------------------------
extern "C" void kernel_launch(void* const* d_in, const int* in_sizes, int n_in,
                              void* d_out, int out_size, void* d_ws, size_t ws_size,
                              hipStream_t stream) {
  const float* x = (const float*)d_in[0];
  const float* qkv_w = (const float*)d_in[1];
  const float* qkv_b = (const float*)d_in[2];
  const float* out_w = (const float*)d_in[3];
  const float* out_b = (const float*)d_in[4];
  float* out = (float*)d_out;

  const size_t SZ = (size_t)B_ * H_ * L_ * D_;  // 4,194,304
  char* p = (char*)d_ws;
  float* Qf = (float*)p;            p += SZ * 4;
  float* Kf = (float*)p;            p += SZ * 4;
  float* Vf = (float*)p;            p += SZ * 4;
  float* kvsum = (float*)p;         p += (size_t)B_ * H_ * NCHUNK * D_ * D_ * 4;
  float* zsum = (float*)p;          p += (size_t)B_ * H_ * NCHUNK * D_ * 4;
  unsigned short* xb = (unsigned short*)p;    p += SZ * 2;            // 4096x1024 bf16
  unsigned short* wqkv = (unsigned short*)p;  p += (size_t)N3_ * E_ * 2;
  unsigned short* wout = (unsigned short*)p;  p += (size_t)E_ * E_ * 2;
  unsigned short* attnb = (unsigned short*)p; p += SZ * 2;            // 4096x1024 bf16

  dim3 blk(256);
  // fp32 -> bf16 converts
  k_cvt_bf16<<<dim3(4096), blk, 0, stream>>>(x, xb, 1048576);
  k_cvt_bf16<<<dim3(3072), blk, 0, stream>>>(qkv_w, wqkv, 786432);
  k_cvt_bf16<<<dim3(1024), blk, 0, stream>>>(out_w, wout, 262144);
  // QKV projection (M=4096, N=3072, K=1024) with scatter epilogue
  k_mfma_gemm<0><<<dim3(N3_ / 128, (B_ * L_) / 128), blk, 0, stream>>>(
      xb, wqkv, qkv_b, nullptr, Qf, Kf, Vf, E_);
  // chunked causal linear attention scan
  k_chunk_sums<<<dim3(B_ * H_ * NCHUNK), blk, 0, stream>>>(Kf, Vf, kvsum, zsum);
  k_prefix<<<dim3(B_ * H_), blk, 0, stream>>>(kvsum, zsum);
  k_chunk_out<<<dim3(B_ * H_ * NCHUNK), blk, 0, stream>>>(Qf, Kf, Vf, kvsum, zsum, attnb);
  // output projection (M=4096, N=1024, K=1024)
  k_mfma_gemm<1><<<dim3(E_ / 128, (B_ * L_) / 128), blk, 0, stream>>>(
      attnb, wout, out_b, out, nullptr, nullptr, nullptr, E_);
}

// Round 4
// 197.056 us; speedup vs baseline: 3.3565x; 1.3637x over previous
//
#include <hip/hip_runtime.h>
#include <hip/hip_bf16.h>
#include <cstdint>

// Problem constants
#define B_ 2
#define L_ 2048
#define E_ 1024
#define H_ 16
#define D_ 64
#define N3_ 3072
#define NCHUNK 32
#define CHUNK 64

typedef __attribute__((ext_vector_type(8))) short bf16x8;
typedef __attribute__((ext_vector_type(4))) float f32x4;

__device__ __forceinline__ unsigned short f2bf(float f) {
  unsigned u = __float_as_uint(f);
  unsigned r = (u + 0x7fffu + ((u >> 16) & 1u)) >> 16;  // RNE
  return (unsigned short)r;
}

// ---------------------------------------------------------------------------
// fp32 -> bf16 conversion (vectorized, exact-grid)
// ---------------------------------------------------------------------------
__global__ __launch_bounds__(256) void k_cvt_bf16(const float* __restrict__ src,
                                                  unsigned short* __restrict__ dst,
                                                  int n4) {
  const int i = blockIdx.x * 256 + threadIdx.x;
  if (i < n4) {
    float4 v = reinterpret_cast<const float4*>(src)[i];
    ushort4 o;
    o.x = f2bf(v.x); o.y = f2bf(v.y); o.z = f2bf(v.z); o.w = f2bf(v.w);
    reinterpret_cast<ushort4*>(dst)[i] = o;
  }
}

// ---------------------------------------------------------------------------
// bf16 MFMA GEMM, m97 structure: C(M,N) = A(M,K) @ B(N,K)^T
// EPI==0: QKV epilogue (bias + relu + eps, scatter BF16 to (b,h,l,d) Q/K/V)
// EPI==1: plain epilogue (bias, store fp32 row-major)
// ---------------------------------------------------------------------------
template <int EPI>
__global__ __launch_bounds__(256) void k_mfma_gemm(
    const unsigned short* __restrict__ A,   // (M,K) bf16 row-major
    const unsigned short* __restrict__ Bm,  // (N,K) bf16 row-major
    const float* __restrict__ bias,         // (N)
    float* __restrict__ O,                  // EPI==1 output (M,N) f32
    unsigned short* __restrict__ Qb, unsigned short* __restrict__ Kb,
    unsigned short* __restrict__ Vb, const int K) {
  __shared__ short As[128 * 32];
  __shared__ short Bs[128 * 32];
  const int tid = threadIdx.x;
  const int lane = tid & 63;
  const int wave = tid >> 6;
  const int wr = wave >> 1, wc = wave & 1;
  const int m0 = blockIdx.y * 128, n0 = blockIdx.x * 128;
  const int srow = tid >> 2;
  const int scol = (tid & 3) << 3;
  f32x4 acc[4][4];
#pragma unroll
  for (int i = 0; i < 4; ++i)
#pragma unroll
    for (int j = 0; j < 4; ++j) acc[i][j] = (f32x4){0.f, 0.f, 0.f, 0.f};

  const int l15 = lane & 15, l16 = lane >> 4;
  const int aoff0 = (wr * 64 + l15) * 32 + l16 * 8;
  const int boff0 = (wc * 64 + l15) * 32 + l16 * 8;

  for (int k0 = 0; k0 < K; k0 += 32) {
    const short* gA = (const short*)&A[(size_t)(m0 + srow) * K + k0 + scol];
    const short* gB = (const short*)&Bm[(size_t)(n0 + srow) * K + k0 + scol];
    __builtin_amdgcn_global_load_lds(
        (const __attribute__((address_space(1))) unsigned int*)gA,
        (__attribute__((address_space(3))) unsigned int*)&As[tid * 8], 16, 0, 0);
    __builtin_amdgcn_global_load_lds(
        (const __attribute__((address_space(1))) unsigned int*)(gA + (size_t)64 * K),
        (__attribute__((address_space(3))) unsigned int*)&As[2048 + tid * 8], 16, 0, 0);
    __builtin_amdgcn_global_load_lds(
        (const __attribute__((address_space(1))) unsigned int*)gB,
        (__attribute__((address_space(3))) unsigned int*)&Bs[tid * 8], 16, 0, 0);
    __builtin_amdgcn_global_load_lds(
        (const __attribute__((address_space(1))) unsigned int*)(gB + (size_t)64 * K),
        (__attribute__((address_space(3))) unsigned int*)&Bs[2048 + tid * 8], 16, 0, 0);
    __syncthreads();
    bf16x8 af[4], bfr[4];
#pragma unroll
    for (int f = 0; f < 4; ++f)
      af[f] = *reinterpret_cast<const bf16x8*>(&As[aoff0 + f * 16 * 32]);
#pragma unroll
    for (int f = 0; f < 4; ++f)
      bfr[f] = *reinterpret_cast<const bf16x8*>(&Bs[boff0 + f * 16 * 32]);
#pragma unroll
    for (int m = 0; m < 4; ++m)
#pragma unroll
      for (int n = 0; n < 4; ++n)
        acc[m][n] = __builtin_amdgcn_mfma_f32_16x16x32_bf16(af[m], bfr[n], acc[m][n], 0, 0, 0);
    __syncthreads();
  }

  const int rbase = l16 * 4;
#pragma unroll
  for (int m = 0; m < 4; ++m) {
#pragma unroll
    for (int n = 0; n < 4; ++n) {
      const int col = n0 + wc * 64 + n * 16 + l15;
      const float bv = bias[col];
#pragma unroll
      for (int j = 0; j < 4; ++j) {
        const int row = m0 + wr * 64 + m * 16 + rbase + j;
        const float val = acc[m][n][j] + bv;
        if (EPI == 0) {
          const int b = row >> 11, l = row & 2047;
          const int t = col >> 10, hd = col & 1023;
          const int h = hd >> 6, d = hd & 63;
          const size_t dst = (((size_t)(b * 16 + h)) * 2048 + l) * 64 + d;
          if (t == 0)      Qb[dst] = f2bf(fmaxf(val, 0.f) + 1e-6f);
          else if (t == 1) Kb[dst] = f2bf(fmaxf(val, 0.f) + 1e-6f);
          else             Vb[dst] = f2bf(val);
        } else {
          O[(size_t)row * 1024 + col] = val;
        }
      }
    }
  }
}

// ---------------------------------------------------------------------------
// Kernel B: per-(bh,chunk) KV-state via MFMA with ones-column trick.
// ST[e'][d] = sum_l V'[l][e'] * K[l][d], e'=0..63 real V, e'=64 ones (=> z).
// Block = 1 chunk, 2 waves (wave w computes e-tiles {2w, 2w+1}; wave0 also z).
// Also persists transposed-V fragments (Vtb) for kernel D.
// ---------------------------------------------------------------------------
__global__ __launch_bounds__(128) void k_chunkB(
    const unsigned short* __restrict__ Kb, const unsigned short* __restrict__ Vb,
    float* __restrict__ ST, unsigned short* __restrict__ Vtb) {
  __shared__ __align__(16) unsigned short Kt[64 * 72];  // (d, l), 72-elem stride
  __shared__ __align__(16) unsigned short Vt[64 * 72];  // (e, l)
  const int tid = threadIdx.x;            // 0..127
  const int lane = tid & 63, w = tid >> 6;
  const int c = lane & 15, g = lane >> 4;
  const int bid = blockIdx.x;
  const int bh = bid >> 5, ch = bid & 31;
  const size_t base = ((size_t)bh * L_ + (size_t)ch * CHUNK) * D_;
  // stage + scalar transpose: thread handles row l = tid>>1, half hf = tid&1
  const int l = tid >> 1, hf = tid & 1;
  bf16x8 kv[4], vv[4];
#pragma unroll
  for (int i = 0; i < 4; ++i) {
    kv[i] = *reinterpret_cast<const bf16x8*>(&Kb[base + (size_t)l * 64 + hf * 32 + i * 8]);
    vv[i] = *reinterpret_cast<const bf16x8*>(&Vb[base + (size_t)l * 64 + hf * 32 + i * 8]);
  }
#pragma unroll
  for (int i = 0; i < 4; ++i)
#pragma unroll
    for (int r = 0; r < 8; ++r) {
      const int d = hf * 32 + i * 8 + r;
      Kt[d * 72 + l] = (unsigned short)kv[i][r];
      Vt[d * 72 + l] = (unsigned short)vv[i][r];
    }
  __syncthreads();
  // fragments: B-op = Kt rows d; A-op = Vt rows e' (both row=lane&15, k=g*8+kh*32)
  bf16x8 kf[4][2], vf[2][2];
#pragma unroll
  for (int dt = 0; dt < 4; ++dt)
#pragma unroll
    for (int kh = 0; kh < 2; ++kh)
      kf[dt][kh] = *reinterpret_cast<const bf16x8*>(&Kt[(dt * 16 + c) * 72 + g * 8 + kh * 32]);
#pragma unroll
  for (int ei = 0; ei < 2; ++ei)
#pragma unroll
    for (int kh = 0; kh < 2; ++kh)
      vf[ei][kh] = *reinterpret_cast<const bf16x8*>(&Vt[((w * 2 + ei) * 16 + c) * 72 + g * 8 + kh * 32]);
  f32x4 acc[2][4];
#pragma unroll
  for (int ei = 0; ei < 2; ++ei)
#pragma unroll
    for (int dt = 0; dt < 4; ++dt) acc[ei][dt] = (f32x4){0.f, 0.f, 0.f, 0.f};
#pragma unroll
  for (int ei = 0; ei < 2; ++ei)
#pragma unroll
    for (int dt = 0; dt < 4; ++dt)
#pragma unroll
      for (int kh = 0; kh < 2; ++kh)
        acc[ei][dt] = __builtin_amdgcn_mfma_f32_16x16x32_bf16(vf[ei][kh], kf[dt][kh], acc[ei][dt], 0, 0, 0);
  const size_t stbase = (size_t)bid * 5120;
#pragma unroll
  for (int ei = 0; ei < 2; ++ei)
#pragma unroll
    for (int dt = 0; dt < 4; ++dt)
#pragma unroll
      for (int r = 0; r < 4; ++r)
        ST[stbase + (size_t)((w * 2 + ei) * 16 + 4 * g + r) * 64 + dt * 16 + c] = acc[ei][dt][r];
  // persist V^T fragments for kernel D (same per-lane layout on both sides)
#pragma unroll
  for (int ei = 0; ei < 2; ++ei)
#pragma unroll
    for (int kh = 0; kh < 2; ++kh)
      *reinterpret_cast<bf16x8*>(&Vtb[(size_t)bid * 4096 + ((w * 2 + ei) * 16 + c) * 64 + g * 8 + kh * 32]) = vf[ei][kh];
  // wave0: z row (e'=64) via all-ones A fragment; only row 64 (g==0, r==0) stored
  if (w == 0) {
    const short one = (c == 0) ? (short)0x3F80 : (short)0;
    bf16x8 of;
#pragma unroll
    for (int r = 0; r < 8; ++r) of[r] = one;
    f32x4 az[4];
#pragma unroll
    for (int dt = 0; dt < 4; ++dt) az[dt] = (f32x4){0.f, 0.f, 0.f, 0.f};
#pragma unroll
    for (int dt = 0; dt < 4; ++dt)
#pragma unroll
      for (int kh = 0; kh < 2; ++kh)
        az[dt] = __builtin_amdgcn_mfma_f32_16x16x32_bf16(of, kf[dt][kh], az[dt], 0, 0, 0);
    if (g == 0) {
#pragma unroll
      for (int dt = 0; dt < 4; ++dt)
        ST[stbase + 64 * 64 + dt * 16 + c] = az[dt][0];
    }
  }
}

// ---------------------------------------------------------------------------
// Kernel C: fp32 exclusive prefix over 32 chunks per (bh); emits bf16 STb.
// Rows 0..63 = KV state, row 64 = z (k-cumsum).
// ---------------------------------------------------------------------------
__global__ __launch_bounds__(256) void k_prefix2(const float* __restrict__ ST,
                                                 unsigned short* __restrict__ STb) {
  const int bh = blockIdx.x;
  const int tid = threadIdx.x;
  float run[16];
#pragma unroll
  for (int j = 0; j < 16; ++j) run[j] = 0.f;
  for (int cc = 0; cc < NCHUNK; ++cc) {
    const size_t base = ((size_t)bh * NCHUNK + cc) * 5120;
    const float* p = ST + base + (size_t)tid * 16;
    unsigned short* qo = STb + base + (size_t)tid * 16;
#pragma unroll
    for (int j4 = 0; j4 < 4; ++j4) {
      float4 t = *reinterpret_cast<const float4*>(&p[j4 * 4]);
      ushort4 o;
      o.x = f2bf(run[j4 * 4 + 0]); o.y = f2bf(run[j4 * 4 + 1]);
      o.z = f2bf(run[j4 * 4 + 2]); o.w = f2bf(run[j4 * 4 + 3]);
      *reinterpret_cast<ushort4*>(&qo[j4 * 4]) = o;
      run[j4 * 4 + 0] += t.x; run[j4 * 4 + 1] += t.y;
      run[j4 * 4 + 2] += t.z; run[j4 * 4 + 3] += t.w;
    }
  }
  if (tid < 64) {
    float rz = 0.f;
    for (int cc = 0; cc < NCHUNK; ++cc) {
      const size_t base = ((size_t)bh * NCHUNK + cc) * 5120 + 4096 + tid;
      float t = ST[base];
      STb[base] = f2bf(rz);
      rz += t;
    }
  }
}

// ---------------------------------------------------------------------------
// Kernel D: per-(bh,chunk) output via MFMA.
// Block = 1 chunk, 4 waves; wave lt owns 16 output rows.
// C1 = mfma(K,Q) (swapped => lane holds P[l][j] slices), causal mask, bf16
// pack -> 2KB/wave swizzled LDS P-bounce -> A-frags.
// acc2[et] += mfma(Q, STb[et]) + mfma(P, V'[et]); et=4 col 64 = den.
// ---------------------------------------------------------------------------
__global__ __launch_bounds__(256) void k_chunkD(
    const unsigned short* __restrict__ Qb, const unsigned short* __restrict__ Kb,
    const unsigned short* __restrict__ Vtb, const unsigned short* __restrict__ STb,
    unsigned short* __restrict__ attnb) {
  __shared__ __align__(16) unsigned short P[4][1024];  // per-wave 16 rows x 128B
  const int tid = threadIdx.x;
  const int lane = tid & 63, lt = tid >> 6;
  const int c = lane & 15, g = lane >> 4;
  const int bid = blockIdx.x;
  const int bh = bid >> 5, ch = bid & 31;
  const int b = bh >> 4, h = bh & 15;
  const size_t qkbase = ((size_t)bh * L_ + (size_t)ch * CHUNK) * D_;
  bf16x8 q[2], k4[4][2], s[5][2], vt[4][2], pa[2];
#pragma unroll
  for (int kh = 0; kh < 2; ++kh)
    q[kh] = *reinterpret_cast<const bf16x8*>(&Qb[qkbase + (size_t)(lt * 16 + c) * 64 + g * 8 + kh * 32]);
#pragma unroll
  for (int jt = 0; jt < 4; ++jt)
#pragma unroll
    for (int kh = 0; kh < 2; ++kh)
      k4[jt][kh] = *reinterpret_cast<const bf16x8*>(&Kb[qkbase + (size_t)(jt * 16 + c) * 64 + g * 8 + kh * 32]);
  const size_t stbase = (size_t)bid * 5120;
#pragma unroll
  for (int et = 0; et < 5; ++et)
#pragma unroll
    for (int kh = 0; kh < 2; ++kh)
      s[et][kh] = *reinterpret_cast<const bf16x8*>(&STb[stbase + (size_t)(et * 16 + c) * 64 + g * 8 + kh * 32]);
#pragma unroll
  for (int et = 0; et < 4; ++et)
#pragma unroll
    for (int kh = 0; kh < 2; ++kh)
      vt[et][kh] = *reinterpret_cast<const bf16x8*>(&Vtb[(size_t)bid * 4096 + (size_t)(et * 16 + c) * 64 + g * 8 + kh * 32]);

  // --- C1: P^T tiles (swapped QK^T), mask, pack, LDS bounce ---
  char* Pb = (char*)&P[lt][0];
  const int swz = (c & 7) << 4;
#pragma unroll
  for (int jt = 0; jt < 4; ++jt) {
    unsigned pk0 = 0, pk1 = 0;
    if (jt <= lt) {  // wave-uniform
      f32x4 a1 = (f32x4){0.f, 0.f, 0.f, 0.f};
#pragma unroll
      for (int kh = 0; kh < 2; ++kh)
        a1 = __builtin_amdgcn_mfma_f32_16x16x32_bf16(k4[jt][kh], q[kh], a1, 0, 0, 0);
      if (jt == lt) {  // causal mask: keep j<=l i.e. 4g+r <= c
#pragma unroll
        for (int r = 0; r < 4; ++r) a1[r] = (4 * g + r <= c) ? a1[r] : 0.f;
      }
      pk0 = (unsigned)f2bf(a1[0]) | ((unsigned)f2bf(a1[1]) << 16);
      pk1 = (unsigned)f2bf(a1[2]) | ((unsigned)f2bf(a1[3]) << 16);
    }
    *reinterpret_cast<unsigned*>(Pb + ((c * 128 + 32 * jt + 8 * g + 0) ^ swz)) = pk0;
    *reinterpret_cast<unsigned*>(Pb + ((c * 128 + 32 * jt + 8 * g + 4) ^ swz)) = pk1;
  }
  // wave-internal exchange: reads see this wave's writes (DS in-order + lgkmcnt)
#pragma unroll
  for (int kh = 0; kh < 2; ++kh)
    pa[kh] = *reinterpret_cast<const bf16x8*>(Pb + (c * 128 + ((16 * g + 64 * kh) ^ swz)));

  // --- C2 + QS fused accumulation ---
  f32x4 acc2[5];
#pragma unroll
  for (int et = 0; et < 5; ++et) acc2[et] = (f32x4){0.f, 0.f, 0.f, 0.f};
  const short one = (c == 0) ? (short)0x3F80 : (short)0;
  bf16x8 of;
#pragma unroll
  for (int r = 0; r < 8; ++r) of[r] = one;
#pragma unroll
  for (int et = 0; et < 5; ++et) {
#pragma unroll
    for (int kh = 0; kh < 2; ++kh) {
      acc2[et] = __builtin_amdgcn_mfma_f32_16x16x32_bf16(q[kh], s[et][kh], acc2[et], 0, 0, 0);
      bf16x8 vv = (et < 4) ? vt[et][kh] : of;
      acc2[et] = __builtin_amdgcn_mfma_f32_16x16x32_bf16(pa[kh], vv, acc2[et], 0, 0, 0);
    }
  }
  // den: col 64 (lanes c==0), broadcast within 16-lane group
  float inv[4];
#pragma unroll
  for (int r = 0; r < 4; ++r) {
    float dv = __shfl(acc2[4][r], lane & 48, 64);
    inv[r] = 1.f / fmaxf(dv, 1e-6f);
  }
  // store attn bf16 (b, l, h*64+e)
  const size_t obase = ((size_t)b * L_ + (size_t)ch * CHUNK + (size_t)lt * 16) * E_ + (size_t)h * 64;
#pragma unroll
  for (int et = 0; et < 4; ++et)
#pragma unroll
    for (int r = 0; r < 4; ++r)
      attnb[obase + (size_t)(4 * g + r) * E_ + et * 16 + c] = f2bf(acc2[et][r] * inv[r]);
}

// ---------------------------------------------------------------------------
extern "C" void kernel_launch(void* const* d_in, const int* in_sizes, int n_in,
                              void* d_out, int out_size, void* d_ws, size_t ws_size,
                              hipStream_t stream) {
  const float* x = (const float*)d_in[0];
  const float* qkv_w = (const float*)d_in[1];
  const float* qkv_b = (const float*)d_in[2];
  const float* out_w = (const float*)d_in[3];
  const float* out_b = (const float*)d_in[4];
  float* out = (float*)d_out;

  const size_t SZ = (size_t)B_ * H_ * L_ * D_;  // 4,194,304
  char* p = (char*)d_ws;
  unsigned short* Qb = (unsigned short*)p;    p += SZ * 2;
  unsigned short* Kb = (unsigned short*)p;    p += SZ * 2;
  unsigned short* Vb = (unsigned short*)p;    p += SZ * 2;
  unsigned short* Vtb = (unsigned short*)p;   p += (size_t)1024 * 4096 * 2;
  float* ST = (float*)p;                      p += (size_t)1024 * 5120 * 4;
  unsigned short* STb = (unsigned short*)p;   p += (size_t)1024 * 5120 * 2;
  unsigned short* xb = (unsigned short*)p;    p += SZ * 2;
  unsigned short* wqkv = (unsigned short*)p;  p += (size_t)N3_ * E_ * 2;
  unsigned short* wout = (unsigned short*)p;  p += (size_t)E_ * E_ * 2;
  unsigned short* attnb = (unsigned short*)p; p += SZ * 2;

  dim3 blk(256);
  k_cvt_bf16<<<dim3(4096), blk, 0, stream>>>(x, xb, 1048576);
  k_cvt_bf16<<<dim3(3072), blk, 0, stream>>>(qkv_w, wqkv, 786432);
  k_cvt_bf16<<<dim3(1024), blk, 0, stream>>>(out_w, wout, 262144);
  // QKV projection (M=4096, N=3072, K=1024), bf16 scatter epilogue
  k_mfma_gemm<0><<<dim3(N3_ / 128, (B_ * L_) / 128), blk, 0, stream>>>(
      xb, wqkv, qkv_b, nullptr, Qb, Kb, Vb, E_);
  // chunked scan, MFMA
  k_chunkB<<<dim3(1024), dim3(128), 0, stream>>>(Kb, Vb, ST, Vtb);
  k_prefix2<<<dim3(B_ * H_), blk, 0, stream>>>(ST, STb);
  k_chunkD<<<dim3(1024), blk, 0, stream>>>(Qb, Kb, Vtb, STb, attnb);
  // output projection (M=4096, N=1024, K=1024)
  k_mfma_gemm<1><<<dim3(E_ / 128, (B_ * L_) / 128), blk, 0, stream>>>(
      attnb, wout, out_b, out, nullptr, nullptr, nullptr, E_);
}

// Round 5
// 180.572 us; speedup vs baseline: 3.6629x; 1.0913x over previous
//
#include <hip/hip_runtime.h>
#include <hip/hip_bf16.h>
#include <cstdint>

// Problem constants
#define B_ 2
#define L_ 2048
#define E_ 1024
#define H_ 16
#define D_ 64
#define N3_ 3072
#define NCHUNK 32
#define CHUNK 64

typedef __attribute__((ext_vector_type(8))) short bf16x8;
typedef __attribute__((ext_vector_type(4))) float f32x4;

__device__ __forceinline__ unsigned short f2bf(float f) {
  unsigned u = __float_as_uint(f);
  unsigned r = (u + 0x7fffu + ((u >> 16) & 1u)) >> 16;  // RNE
  return (unsigned short)r;
}

// ---------------------------------------------------------------------------
// fp32 -> bf16 conversion (vectorized, exact-grid)
// ---------------------------------------------------------------------------
__global__ __launch_bounds__(256) void k_cvt_bf16(const float* __restrict__ src,
                                                  unsigned short* __restrict__ dst,
                                                  int n4) {
  const int i = blockIdx.x * 256 + threadIdx.x;
  if (i < n4) {
    float4 v = reinterpret_cast<const float4*>(src)[i];
    ushort4 o;
    o.x = f2bf(v.x); o.y = f2bf(v.y); o.z = f2bf(v.z); o.w = f2bf(v.w);
    reinterpret_cast<ushort4*>(dst)[i] = o;
  }
}

// ---------------------------------------------------------------------------
// QKV GEMM: 256x256 tile, BK=64, 8 waves (2M x 4N), 8-phase schedule with
// counted vmcnt (T3+T4), LDS XOR-swizzle (T2), setprio (T5).
// C(M,N) = A(M,K) @ B(N,K)^T, K=1024. Epilogue: bias+relu+eps, bf16 scatter.
// Schedule bookkeeping (per-wave gload_lds calls, 2 per half-tile):
//   prologue: stage t0{A0,A1,B0,B1}, t1{A0,A1}; vmcnt(4) -> t0 resident.
//   tile t (dbuf d=t&1): ph1 stage B0(t+1)->d^1, ph2 B1(t+1)->d^1,
//     ph3 A0(t+2)->d (safe: tile-t ds_reads closed by ph2 barrier),
//     ph4 A1(t+2)->d, then vmcnt(4) retires A(t+1)+B(t+1) -> t+1 resident.
// ---------------------------------------------------------------------------
__global__ __launch_bounds__(512, 2) void k_gemm256_qkv(
    const unsigned short* __restrict__ A,   // (4096,1024) bf16
    const unsigned short* __restrict__ Bm,  // (3072,1024) bf16
    const float* __restrict__ bias,
    unsigned short* __restrict__ Qb, unsigned short* __restrict__ Kb,
    unsigned short* __restrict__ Vb) {
  __shared__ short As[2][16384];  // [dbuf][256 rows x 64 k]
  __shared__ short Bs[2][16384];
  const int tid = threadIdx.x;
  const int lane = tid & 63, wave = tid >> 6;
  const int wm = wave >> 2, wn = wave & 3;       // 2 x 4 wave grid
  const int m0 = blockIdx.y * 256, n0 = blockIdx.x * 256;
  const int srow = tid >> 3, scol = (tid & 7) * 8;  // staging: 64 rows/inst
  const int ssw = (srow & 7) * 8;                   // source pre-swizzle
  const int l15 = lane & 15, l16 = lane >> 4;
  const int sw = (l15 & 7) * 8;                     // read-side swizzle
  const int NT = 16;                                // 1024 / 64

  f32x4 acc[8][4];
#pragma unroll
  for (int i = 0; i < 8; ++i)
#pragma unroll
    for (int j = 0; j < 4; ++j) acc[i][j] = (f32x4){0.f, 0.f, 0.f, 0.f};

  auto stage = [&](short (&S)[2][16384], const unsigned short* G, int R0,
                   int d, int h, int kt) {
#pragma unroll
    for (int i = 0; i < 2; ++i) {
      const int r = h * 128 + i * 64 + srow;
      const unsigned short* src = &G[(size_t)(R0 + r) * 1024 + kt * 64 + (scol ^ ssw)];
      short* dst = &S[d][r * 64 + scol];
      __builtin_amdgcn_global_load_lds(
          (const __attribute__((address_space(1))) unsigned int*)src,
          (__attribute__((address_space(3))) unsigned int*)dst, 16, 0, 0);
    }
  };
  auto lda = [&](bf16x8 (&dv)[8], int d, int kh) {
#pragma unroll
    for (int mi = 0; mi < 8; ++mi) {
      const int r = wm * 128 + mi * 16 + l15;
      dv[mi] = *reinterpret_cast<const bf16x8*>(&As[d][r * 64 + ((l16 * 8 + kh * 32) ^ sw)]);
    }
  };
  auto ldb = [&](bf16x8 (&dv)[4], int d, int kh) {
#pragma unroll
    for (int ni = 0; ni < 4; ++ni) {
      const int r = wn * 64 + ni * 16 + l15;
      dv[ni] = *reinterpret_cast<const bf16x8*>(&Bs[d][r * 64 + ((l16 * 8 + kh * 32) ^ sw)]);
    }
  };
  auto quad = [&](const bf16x8 (&af)[8], const bf16x8 (&bf)[4], int nlo) {
    __builtin_amdgcn_s_setprio(1);
#pragma unroll
    for (int mi = 0; mi < 8; ++mi)
#pragma unroll
      for (int nn = 0; nn < 2; ++nn)
        acc[mi][nlo + nn] = __builtin_amdgcn_mfma_f32_16x16x32_bf16(
            af[mi], bf[nlo + nn], acc[mi][nlo + nn], 0, 0, 0);
    __builtin_amdgcn_s_setprio(0);
  };

  // prologue
  stage(As, A, m0, 0, 0, 0); stage(As, A, m0, 0, 1, 0);
  stage(Bs, Bm, n0, 0, 0, 0); stage(Bs, Bm, n0, 0, 1, 0);
  stage(As, A, m0, 1, 0, 1); stage(As, A, m0, 1, 1, 1);
  asm volatile("s_waitcnt vmcnt(4)" ::: "memory");
  __builtin_amdgcn_s_barrier();

  bf16x8 af0[8], af1[8], bf0[4], bf1[4];
  for (int t = 0; t < NT; ++t) {
    const int d = t & 1;
    // ph1: ds-read kh0; stage B0(t+1); MFMA ni{0,1} kh0
    lda(af0, d, 0); ldb(bf0, d, 0);
    if (t + 1 < NT) stage(Bs, Bm, n0, d ^ 1, 0, t + 1);
    __builtin_amdgcn_s_barrier();
    asm volatile("s_waitcnt lgkmcnt(0)" ::: "memory");
    __builtin_amdgcn_sched_barrier(0);
    quad(af0, bf0, 0);
    __builtin_amdgcn_s_barrier();
    // ph2: ds-read kh1; stage B1(t+1); MFMA ni{2,3} kh0
    lda(af1, d, 1); ldb(bf1, d, 1);
    if (t + 1 < NT) stage(Bs, Bm, n0, d ^ 1, 1, t + 1);
    __builtin_amdgcn_s_barrier();
    asm volatile("s_waitcnt lgkmcnt(0)" ::: "memory");
    __builtin_amdgcn_sched_barrier(0);
    quad(af0, bf0, 2);
    __builtin_amdgcn_s_barrier();
    // ph3: stage A0(t+2) into d (tile-t reads closed by ph2 barrier)
    if (t + 2 < NT) stage(As, A, m0, d, 0, t + 2);
    quad(af1, bf1, 0);
    __builtin_amdgcn_s_barrier();
    // ph4: stage A1(t+2); MFMA; counted vmcnt -> tile t+1 resident
    if (t + 2 < NT) stage(As, A, m0, d, 1, t + 2);
    quad(af1, bf1, 2);
    if (t + 2 < NT) asm volatile("s_waitcnt vmcnt(4)" ::: "memory");
    else            asm volatile("s_waitcnt vmcnt(0)" ::: "memory");
    __builtin_amdgcn_s_barrier();
  }

  // epilogue: scatter bf16 Q/K/V with bias + relu + eps
#pragma unroll
  for (int mi = 0; mi < 8; ++mi) {
#pragma unroll
    for (int ni = 0; ni < 4; ++ni) {
      const int col = n0 + wn * 64 + ni * 16 + l15;
      const float bv = bias[col];
      const int t = col >> 10, hd = col & 1023;
      const int h = hd >> 6, dd = hd & 63;
#pragma unroll
      for (int j = 0; j < 4; ++j) {
        const int row = m0 + wm * 128 + mi * 16 + l16 * 4 + j;
        const float val = acc[mi][ni][j] + bv;
        const int b = row >> 11, l = row & 2047;
        const size_t dst = (((size_t)(b * 16 + h)) * 2048 + l) * 64 + dd;
        if (t == 0)      Qb[dst] = f2bf(fmaxf(val, 0.f) + 1e-6f);
        else if (t == 1) Kb[dst] = f2bf(fmaxf(val, 0.f) + 1e-6f);
        else             Vb[dst] = f2bf(val);
      }
    }
  }
}

// ---------------------------------------------------------------------------
// Output GEMM (m97 structure): C(M,N) = A(M,K) @ B(N,K)^T, fp32 out + bias.
// ---------------------------------------------------------------------------
__global__ __launch_bounds__(256) void k_gemm_out(
    const unsigned short* __restrict__ A, const unsigned short* __restrict__ Bm,
    const float* __restrict__ bias, float* __restrict__ O, const int K) {
  __shared__ short As[128 * 32];
  __shared__ short Bs[128 * 32];
  const int tid = threadIdx.x;
  const int lane = tid & 63;
  const int wave = tid >> 6;
  const int wr = wave >> 1, wc = wave & 1;
  const int m0 = blockIdx.y * 128, n0 = blockIdx.x * 128;
  const int srow = tid >> 2;
  const int scol = (tid & 3) << 3;
  f32x4 acc[4][4];
#pragma unroll
  for (int i = 0; i < 4; ++i)
#pragma unroll
    for (int j = 0; j < 4; ++j) acc[i][j] = (f32x4){0.f, 0.f, 0.f, 0.f};

  const int l15 = lane & 15, l16 = lane >> 4;
  const int aoff0 = (wr * 64 + l15) * 32 + l16 * 8;
  const int boff0 = (wc * 64 + l15) * 32 + l16 * 8;

  for (int k0 = 0; k0 < K; k0 += 32) {
    const short* gA = (const short*)&A[(size_t)(m0 + srow) * K + k0 + scol];
    const short* gB = (const short*)&Bm[(size_t)(n0 + srow) * K + k0 + scol];
    __builtin_amdgcn_global_load_lds(
        (const __attribute__((address_space(1))) unsigned int*)gA,
        (__attribute__((address_space(3))) unsigned int*)&As[tid * 8], 16, 0, 0);
    __builtin_amdgcn_global_load_lds(
        (const __attribute__((address_space(1))) unsigned int*)(gA + (size_t)64 * K),
        (__attribute__((address_space(3))) unsigned int*)&As[2048 + tid * 8], 16, 0, 0);
    __builtin_amdgcn_global_load_lds(
        (const __attribute__((address_space(1))) unsigned int*)gB,
        (__attribute__((address_space(3))) unsigned int*)&Bs[tid * 8], 16, 0, 0);
    __builtin_amdgcn_global_load_lds(
        (const __attribute__((address_space(1))) unsigned int*)(gB + (size_t)64 * K),
        (__attribute__((address_space(3))) unsigned int*)&Bs[2048 + tid * 8], 16, 0, 0);
    __syncthreads();
    bf16x8 af[4], bfr[4];
#pragma unroll
    for (int f = 0; f < 4; ++f)
      af[f] = *reinterpret_cast<const bf16x8*>(&As[aoff0 + f * 16 * 32]);
#pragma unroll
    for (int f = 0; f < 4; ++f)
      bfr[f] = *reinterpret_cast<const bf16x8*>(&Bs[boff0 + f * 16 * 32]);
#pragma unroll
    for (int m = 0; m < 4; ++m)
#pragma unroll
      for (int n = 0; n < 4; ++n)
        acc[m][n] = __builtin_amdgcn_mfma_f32_16x16x32_bf16(af[m], bfr[n], acc[m][n], 0, 0, 0);
    __syncthreads();
  }

  const int rbase = l16 * 4;
#pragma unroll
  for (int m = 0; m < 4; ++m) {
#pragma unroll
    for (int n = 0; n < 4; ++n) {
      const int col = n0 + wc * 64 + n * 16 + l15;
      const float bv = bias[col];
#pragma unroll
      for (int j = 0; j < 4; ++j) {
        const int row = m0 + wr * 64 + m * 16 + rbase + j;
        O[(size_t)row * 1024 + col] = acc[m][n][j] + bv;
      }
    }
  }
}

// ---------------------------------------------------------------------------
// Kernel B: per-(bh,chunk) KV-state via MFMA with ones-column trick.
// ---------------------------------------------------------------------------
__global__ __launch_bounds__(128) void k_chunkB(
    const unsigned short* __restrict__ Kb, const unsigned short* __restrict__ Vb,
    float* __restrict__ ST, unsigned short* __restrict__ Vtb) {
  __shared__ __align__(16) unsigned short Kt[64 * 72];  // (d, l)
  __shared__ __align__(16) unsigned short Vt[64 * 72];  // (e, l)
  const int tid = threadIdx.x;
  const int lane = tid & 63, w = tid >> 6;
  const int c = lane & 15, g = lane >> 4;
  const int bid = blockIdx.x;
  const int bh = bid >> 5, ch = bid & 31;
  const size_t base = ((size_t)bh * L_ + (size_t)ch * CHUNK) * D_;
  const int l = tid >> 1, hf = tid & 1;
  bf16x8 kv[4], vv[4];
#pragma unroll
  for (int i = 0; i < 4; ++i) {
    kv[i] = *reinterpret_cast<const bf16x8*>(&Kb[base + (size_t)l * 64 + hf * 32 + i * 8]);
    vv[i] = *reinterpret_cast<const bf16x8*>(&Vb[base + (size_t)l * 64 + hf * 32 + i * 8]);
  }
#pragma unroll
  for (int i = 0; i < 4; ++i)
#pragma unroll
    for (int r = 0; r < 8; ++r) {
      const int d = hf * 32 + i * 8 + r;
      Kt[d * 72 + l] = (unsigned short)kv[i][r];
      Vt[d * 72 + l] = (unsigned short)vv[i][r];
    }
  __syncthreads();
  bf16x8 kf[4][2], vf[2][2];
#pragma unroll
  for (int dt = 0; dt < 4; ++dt)
#pragma unroll
    for (int kh = 0; kh < 2; ++kh)
      kf[dt][kh] = *reinterpret_cast<const bf16x8*>(&Kt[(dt * 16 + c) * 72 + g * 8 + kh * 32]);
#pragma unroll
  for (int ei = 0; ei < 2; ++ei)
#pragma unroll
    for (int kh = 0; kh < 2; ++kh)
      vf[ei][kh] = *reinterpret_cast<const bf16x8*>(&Vt[((w * 2 + ei) * 16 + c) * 72 + g * 8 + kh * 32]);
  f32x4 acc[2][4];
#pragma unroll
  for (int ei = 0; ei < 2; ++ei)
#pragma unroll
    for (int dt = 0; dt < 4; ++dt) acc[ei][dt] = (f32x4){0.f, 0.f, 0.f, 0.f};
#pragma unroll
  for (int ei = 0; ei < 2; ++ei)
#pragma unroll
    for (int dt = 0; dt < 4; ++dt)
#pragma unroll
      for (int kh = 0; kh < 2; ++kh)
        acc[ei][dt] = __builtin_amdgcn_mfma_f32_16x16x32_bf16(vf[ei][kh], kf[dt][kh], acc[ei][dt], 0, 0, 0);
  const size_t stbase = (size_t)bid * 5120;
#pragma unroll
  for (int ei = 0; ei < 2; ++ei)
#pragma unroll
    for (int dt = 0; dt < 4; ++dt)
#pragma unroll
      for (int r = 0; r < 4; ++r)
        ST[stbase + (size_t)((w * 2 + ei) * 16 + 4 * g + r) * 64 + dt * 16 + c] = acc[ei][dt][r];
#pragma unroll
  for (int ei = 0; ei < 2; ++ei)
#pragma unroll
    for (int kh = 0; kh < 2; ++kh)
      *reinterpret_cast<bf16x8*>(&Vtb[(size_t)bid * 4096 + ((w * 2 + ei) * 16 + c) * 64 + g * 8 + kh * 32]) = vf[ei][kh];
  if (w == 0) {
    const short one = (c == 0) ? (short)0x3F80 : (short)0;
    bf16x8 of;
#pragma unroll
    for (int r = 0; r < 8; ++r) of[r] = one;
    f32x4 az[4];
#pragma unroll
    for (int dt = 0; dt < 4; ++dt) az[dt] = (f32x4){0.f, 0.f, 0.f, 0.f};
#pragma unroll
    for (int dt = 0; dt < 4; ++dt)
#pragma unroll
      for (int kh = 0; kh < 2; ++kh)
        az[dt] = __builtin_amdgcn_mfma_f32_16x16x32_bf16(of, kf[dt][kh], az[dt], 0, 0, 0);
    if (g == 0) {
#pragma unroll
      for (int dt = 0; dt < 4; ++dt)
        ST[stbase + 64 * 64 + dt * 16 + c] = az[dt][0];
    }
  }
}

// ---------------------------------------------------------------------------
// Kernel C: element-parallel exclusive prefix over 32 chunks per (bh).
// grid (32, 17): one thread per state element, loop over chunks.
// ---------------------------------------------------------------------------
__global__ __launch_bounds__(256) void k_prefix2(const float* __restrict__ ST,
                                                 unsigned short* __restrict__ STb) {
  const int bh = blockIdx.x;
  const int e = blockIdx.y * 256 + threadIdx.x;
  if (e >= 4160) return;
  const size_t base = (size_t)bh * NCHUNK * 5120 + e;
  float run = 0.f;
  for (int cc = 0; cc < NCHUNK; ++cc) {
    const float t = ST[base + (size_t)cc * 5120];
    STb[base + (size_t)cc * 5120] = f2bf(run);
    run += t;
  }
}

// ---------------------------------------------------------------------------
// Kernel D: per-(bh,chunk) output via MFMA (swapped QK^T + ones-column den).
// ---------------------------------------------------------------------------
__global__ __launch_bounds__(256) void k_chunkD(
    const unsigned short* __restrict__ Qb, const unsigned short* __restrict__ Kb,
    const unsigned short* __restrict__ Vtb, const unsigned short* __restrict__ STb,
    unsigned short* __restrict__ attnb) {
  __shared__ __align__(16) unsigned short P[4][1024];
  const int tid = threadIdx.x;
  const int lane = tid & 63, lt = tid >> 6;
  const int c = lane & 15, g = lane >> 4;
  const int bid = blockIdx.x;
  const int bh = bid >> 5, ch = bid & 31;
  const int b = bh >> 4, h = bh & 15;
  const size_t qkbase = ((size_t)bh * L_ + (size_t)ch * CHUNK) * D_;
  bf16x8 q[2], k4[4][2], s[5][2], vt[4][2], pa[2];
#pragma unroll
  for (int kh = 0; kh < 2; ++kh)
    q[kh] = *reinterpret_cast<const bf16x8*>(&Qb[qkbase + (size_t)(lt * 16 + c) * 64 + g * 8 + kh * 32]);
#pragma unroll
  for (int jt = 0; jt < 4; ++jt)
#pragma unroll
    for (int kh = 0; kh < 2; ++kh)
      k4[jt][kh] = *reinterpret_cast<const bf16x8*>(&Kb[qkbase + (size_t)(jt * 16 + c) * 64 + g * 8 + kh * 32]);
  const size_t stbase = (size_t)bid * 5120;
#pragma unroll
  for (int et = 0; et < 5; ++et)
#pragma unroll
    for (int kh = 0; kh < 2; ++kh)
      s[et][kh] = *reinterpret_cast<const bf16x8*>(&STb[stbase + (size_t)(et * 16 + c) * 64 + g * 8 + kh * 32]);
#pragma unroll
  for (int et = 0; et < 4; ++et)
#pragma unroll
    for (int kh = 0; kh < 2; ++kh)
      vt[et][kh] = *reinterpret_cast<const bf16x8*>(&Vtb[(size_t)bid * 4096 + (size_t)(et * 16 + c) * 64 + g * 8 + kh * 32]);

  char* Pb = (char*)&P[lt][0];
  const int swz = (c & 7) << 4;
#pragma unroll
  for (int jt = 0; jt < 4; ++jt) {
    unsigned pk0 = 0, pk1 = 0;
    if (jt <= lt) {
      f32x4 a1 = (f32x4){0.f, 0.f, 0.f, 0.f};
#pragma unroll
      for (int kh = 0; kh < 2; ++kh)
        a1 = __builtin_amdgcn_mfma_f32_16x16x32_bf16(k4[jt][kh], q[kh], a1, 0, 0, 0);
      if (jt == lt) {
#pragma unroll
        for (int r = 0; r < 4; ++r) a1[r] = (4 * g + r <= c) ? a1[r] : 0.f;
      }
      pk0 = (unsigned)f2bf(a1[0]) | ((unsigned)f2bf(a1[1]) << 16);
      pk1 = (unsigned)f2bf(a1[2]) | ((unsigned)f2bf(a1[3]) << 16);
    }
    *reinterpret_cast<unsigned*>(Pb + ((c * 128 + 32 * jt + 8 * g + 0) ^ swz)) = pk0;
    *reinterpret_cast<unsigned*>(Pb + ((c * 128 + 32 * jt + 8 * g + 4) ^ swz)) = pk1;
  }
#pragma unroll
  for (int kh = 0; kh < 2; ++kh)
    pa[kh] = *reinterpret_cast<const bf16x8*>(Pb + (c * 128 + ((16 * g + 64 * kh) ^ swz)));

  f32x4 acc2[5];
#pragma unroll
  for (int et = 0; et < 5; ++et) acc2[et] = (f32x4){0.f, 0.f, 0.f, 0.f};
  const short one = (c == 0) ? (short)0x3F80 : (short)0;
  bf16x8 of;
#pragma unroll
  for (int r = 0; r < 8; ++r) of[r] = one;
#pragma unroll
  for (int et = 0; et < 5; ++et) {
#pragma unroll
    for (int kh = 0; kh < 2; ++kh) {
      acc2[et] = __builtin_amdgcn_mfma_f32_16x16x32_bf16(q[kh], s[et][kh], acc2[et], 0, 0, 0);
      bf16x8 vv = (et < 4) ? vt[et][kh] : of;
      acc2[et] = __builtin_amdgcn_mfma_f32_16x16x32_bf16(pa[kh], vv, acc2[et], 0, 0, 0);
    }
  }
  float inv[4];
#pragma unroll
  for (int r = 0; r < 4; ++r) {
    float dv = __shfl(acc2[4][r], lane & 48, 64);
    inv[r] = 1.f / fmaxf(dv, 1e-6f);
  }
  const size_t obase = ((size_t)b * L_ + (size_t)ch * CHUNK + (size_t)lt * 16) * E_ + (size_t)h * 64;
#pragma unroll
  for (int et = 0; et < 4; ++et)
#pragma unroll
    for (int r = 0; r < 4; ++r)
      attnb[obase + (size_t)(4 * g + r) * E_ + et * 16 + c] = f2bf(acc2[et][r] * inv[r]);
}

// ---------------------------------------------------------------------------
extern "C" void kernel_launch(void* const* d_in, const int* in_sizes, int n_in,
                              void* d_out, int out_size, void* d_ws, size_t ws_size,
                              hipStream_t stream) {
  const float* x = (const float*)d_in[0];
  const float* qkv_w = (const float*)d_in[1];
  const float* qkv_b = (const float*)d_in[2];
  const float* out_w = (const float*)d_in[3];
  const float* out_b = (const float*)d_in[4];
  float* out = (float*)d_out;

  const size_t SZ = (size_t)B_ * H_ * L_ * D_;  // 4,194,304
  char* p = (char*)d_ws;
  unsigned short* Qb = (unsigned short*)p;    p += SZ * 2;
  unsigned short* Kb = (unsigned short*)p;    p += SZ * 2;
  unsigned short* Vb = (unsigned short*)p;    p += SZ * 2;
  unsigned short* Vtb = (unsigned short*)p;   p += (size_t)1024 * 4096 * 2;
  float* ST = (float*)p;                      p += (size_t)1024 * 5120 * 4;
  unsigned short* STb = (unsigned short*)p;   p += (size_t)1024 * 5120 * 2;
  unsigned short* xb = (unsigned short*)p;    p += SZ * 2;
  unsigned short* wqkv = (unsigned short*)p;  p += (size_t)N3_ * E_ * 2;
  unsigned short* wout = (unsigned short*)p;  p += (size_t)E_ * E_ * 2;
  unsigned short* attnb = (unsigned short*)p; p += SZ * 2;

  dim3 blk(256);
  k_cvt_bf16<<<dim3(4096), blk, 0, stream>>>(x, xb, 1048576);
  k_cvt_bf16<<<dim3(3072), blk, 0, stream>>>(qkv_w, wqkv, 786432);
  k_cvt_bf16<<<dim3(1024), blk, 0, stream>>>(out_w, wout, 262144);
  // QKV projection (M=4096, N=3072, K=1024), 256^2 8-phase
  k_gemm256_qkv<<<dim3(N3_ / 256, (B_ * L_) / 256), dim3(512), 0, stream>>>(
      xb, wqkv, qkv_b, Qb, Kb, Vb);
  // chunked scan, MFMA
  k_chunkB<<<dim3(1024), dim3(128), 0, stream>>>(Kb, Vb, ST, Vtb);
  k_prefix2<<<dim3(32, 17), blk, 0, stream>>>(ST, STb);
  k_chunkD<<<dim3(1024), blk, 0, stream>>>(Qb, Kb, Vtb, STb, attnb);
  // output projection (M=4096, N=1024, K=1024), m97 structure
  k_gemm_out<<<dim3(E_ / 128, (B_ * L_) / 128), blk, 0, stream>>>(
      attnb, wout, out_b, out, E_);
}

// Round 6
// 173.590 us; speedup vs baseline: 3.8103x; 1.0402x over previous
//
#include <hip/hip_runtime.h>
#include <hip/hip_bf16.h>
#include <cstdint>

// Problem constants
#define B_ 2
#define L_ 2048
#define E_ 1024
#define H_ 16
#define D_ 64
#define N3_ 3072
#define NCHUNK 32
#define CHUNK 64

typedef __attribute__((ext_vector_type(8))) short bf16x8;
typedef __attribute__((ext_vector_type(4))) float f32x4;

__device__ __forceinline__ unsigned short f2bf(float f) {
  unsigned u = __float_as_uint(f);
  unsigned r = (u + 0x7fffu + ((u >> 16) & 1u)) >> 16;  // RNE
  return (unsigned short)r;
}

// ---------------------------------------------------------------------------
// fp32 -> bf16 conversion, all three tensors in one launch.
// ranges (float4 units): x 1048576 | qkv_w 786432 | out_w 262144
// ---------------------------------------------------------------------------
__global__ __launch_bounds__(256) void k_cvt_all(
    const float* __restrict__ x, const float* __restrict__ qkv_w,
    const float* __restrict__ out_w, unsigned short* __restrict__ xb,
    unsigned short* __restrict__ wqkv, unsigned short* __restrict__ wout) {
  const int i = blockIdx.x * 256 + threadIdx.x;
  const float* src;
  unsigned short* dst;
  int j;
  if (i < 1048576)      { src = x;     dst = xb;   j = i; }
  else if (i < 1835008) { src = qkv_w; dst = wqkv; j = i - 1048576; }
  else                  { src = out_w; dst = wout; j = i - 1835008; }
  float4 v = reinterpret_cast<const float4*>(src)[j];
  ushort4 o;
  o.x = f2bf(v.x); o.y = f2bf(v.y); o.z = f2bf(v.z); o.w = f2bf(v.w);
  reinterpret_cast<ushort4*>(dst)[j] = o;
}

// ---------------------------------------------------------------------------
// QKV GEMM: 256x192 tile, BK=64, 8 waves (2M x 4N, wave tile 128x48),
// 8-phase schedule, counted vmcnt, LDS XOR-swizzle, setprio, XCD swizzle.
// Grid 16x16 = 256 blocks = exactly 1/CU.
// vmcnt ledger (gload_lds insts): per tile B(t+1)x3 (ph1), A(t+2)x4 (ph3/4);
// vmcnt(4) at ph4 retires A(t+1)+B(t+1), leaves A(t+2) in flight.
// ---------------------------------------------------------------------------
__global__ __launch_bounds__(512, 2) void k_gemm256_qkv(
    const unsigned short* __restrict__ A,   // (4096,1024) bf16
    const unsigned short* __restrict__ Bm,  // (3072,1024) bf16
    const float* __restrict__ bias,
    unsigned short* __restrict__ Qb, unsigned short* __restrict__ Kb,
    unsigned short* __restrict__ Vb) {
  __shared__ short As[2][256 * 64];
  __shared__ short Bs[2][192 * 64];
  const int tid = threadIdx.x;
  const int lane = tid & 63, wave = tid >> 6;
  const int wm = wave >> 2, wn = wave & 3;
  // bijective XCD chunk swizzle over 256 blocks (32 consecutive per XCD)
  const int bid0 = blockIdx.y * 16 + blockIdx.x;
  const int bid = (bid0 & 7) * 32 + (bid0 >> 3);
  const int m0 = (bid >> 4) * 256, n0 = (bid & 15) * 192;
  const int srow = tid >> 3, scol = (tid & 7) * 8;  // 64 rows / gload inst
  const int ssw = (srow & 7) * 8;                   // source pre-swizzle
  const int l15 = lane & 15, l16 = lane >> 4;
  const int sw = (l15 & 7) * 8;                     // read-side swizzle
  const int NT = 16;                                // 1024/64 K-tiles

  f32x4 acc[8][3];
#pragma unroll
  for (int i = 0; i < 8; ++i)
#pragma unroll
    for (int j = 0; j < 3; ++j) acc[i][j] = (f32x4){0.f, 0.f, 0.f, 0.f};

  auto stageA = [&](int d, int kt) {  // 4 insts
#pragma unroll
    for (int i = 0; i < 4; ++i) {
      const int r = i * 64 + srow;
      const unsigned short* src = &A[(size_t)(m0 + r) * 1024 + kt * 64 + (scol ^ ssw)];
      __builtin_amdgcn_global_load_lds(
          (const __attribute__((address_space(1))) unsigned int*)src,
          (__attribute__((address_space(3))) unsigned int*)&As[d][r * 64 + scol], 16, 0, 0);
    }
  };
  auto stageB = [&](int d, int kt) {  // 3 insts
#pragma unroll
    for (int i = 0; i < 3; ++i) {
      const int r = i * 64 + srow;
      const unsigned short* src = &Bm[(size_t)(n0 + r) * 1024 + kt * 64 + (scol ^ ssw)];
      __builtin_amdgcn_global_load_lds(
          (const __attribute__((address_space(1))) unsigned int*)src,
          (__attribute__((address_space(3))) unsigned int*)&Bs[d][r * 64 + scol], 16, 0, 0);
    }
  };
  auto lda = [&](bf16x8 (&dv)[8], int d, int kh) {
#pragma unroll
    for (int mi = 0; mi < 8; ++mi) {
      const int r = wm * 128 + mi * 16 + l15;
      dv[mi] = *reinterpret_cast<const bf16x8*>(&As[d][r * 64 + ((l16 * 8 + kh * 32) ^ sw)]);
    }
  };
  auto ldb = [&](bf16x8 (&dv)[3], int d, int kh) {
#pragma unroll
    for (int ni = 0; ni < 3; ++ni) {
      const int r = wn * 48 + ni * 16 + l15;
      dv[ni] = *reinterpret_cast<const bf16x8*>(&Bs[d][r * 64 + ((l16 * 8 + kh * 32) ^ sw)]);
    }
  };
  auto quad = [&](const bf16x8 (&af)[8], const bf16x8 (&bf)[3], int nb, int ne) {
    __builtin_amdgcn_s_setprio(1);
#pragma unroll
    for (int mi = 0; mi < 8; ++mi)
      for (int nn = nb; nn < ne; ++nn)
        acc[mi][nn] = __builtin_amdgcn_mfma_f32_16x16x32_bf16(af[mi], bf[nn], acc[mi][nn], 0, 0, 0);
    __builtin_amdgcn_s_setprio(0);
  };

  // prologue: A0,B0,A1 in flight; vmcnt(4) -> t0 resident, A1 outstanding
  stageA(0, 0); stageB(0, 0); stageA(1, 1);
  asm volatile("s_waitcnt vmcnt(4)" ::: "memory");
  __builtin_amdgcn_s_barrier();

  bf16x8 af0[8], af1[8], bf0[3], bf1[3];
  for (int t = 0; t < NT; ++t) {
    const int d = t & 1;
    // ph1: ds-read kh0; stage B(t+1)->d^1; MFMA kh0 ni{0,1}
    lda(af0, d, 0); ldb(bf0, d, 0);
    if (t + 1 < NT) stageB(d ^ 1, t + 1);
    __builtin_amdgcn_s_barrier();
    asm volatile("s_waitcnt lgkmcnt(0)" ::: "memory");
    __builtin_amdgcn_sched_barrier(0);
    quad(af0, bf0, 0, 2);
    __builtin_amdgcn_s_barrier();
    // ph2: ds-read kh1; MFMA kh0 ni{2}
    lda(af1, d, 1); ldb(bf1, d, 1);
    __builtin_amdgcn_s_barrier();
    asm volatile("s_waitcnt lgkmcnt(0)" ::: "memory");
    __builtin_amdgcn_sched_barrier(0);
    quad(af0, bf0, 2, 3);
    __builtin_amdgcn_s_barrier();
    // ph3: stage A(t+2)->d (tile-t A reads closed by ph2); MFMA kh1 ni{0,1}
    if (t + 2 < NT) stageA(d, t + 2);
    quad(af1, bf1, 0, 2);
    __builtin_amdgcn_s_barrier();
    // ph4: MFMA kh1 ni{2}; counted vmcnt -> t+1 resident
    quad(af1, bf1, 2, 3);
    if (t + 2 < NT) asm volatile("s_waitcnt vmcnt(4)" ::: "memory");
    else            asm volatile("s_waitcnt vmcnt(0)" ::: "memory");
    __builtin_amdgcn_s_barrier();
  }

  // epilogue: scatter bf16 Q/K/V with bias + relu + eps
#pragma unroll
  for (int mi = 0; mi < 8; ++mi) {
#pragma unroll
    for (int ni = 0; ni < 3; ++ni) {
      const int col = n0 + wn * 48 + ni * 16 + l15;
      const float bv = bias[col];
      const int t = col >> 10, hd = col & 1023;
      const int h = hd >> 6, dd = hd & 63;
#pragma unroll
      for (int j = 0; j < 4; ++j) {
        const int row = m0 + wm * 128 + mi * 16 + l16 * 4 + j;
        const float val = acc[mi][ni][j] + bv;
        const int b = row >> 11, l = row & 2047;
        const size_t dst = (((size_t)(b * 16 + h)) * 2048 + l) * 64 + dd;
        if (t == 0)      Qb[dst] = f2bf(fmaxf(val, 0.f) + 1e-6f);
        else if (t == 1) Kb[dst] = f2bf(fmaxf(val, 0.f) + 1e-6f);
        else             Vb[dst] = f2bf(val);
      }
    }
  }
}

// ---------------------------------------------------------------------------
// Output GEMM (m97 structure): C(M,N) = A(M,K) @ B(N,K)^T, fp32 out + bias.
// ---------------------------------------------------------------------------
__global__ __launch_bounds__(256) void k_gemm_out(
    const unsigned short* __restrict__ A, const unsigned short* __restrict__ Bm,
    const float* __restrict__ bias, float* __restrict__ O, const int K) {
  __shared__ short As[128 * 32];
  __shared__ short Bs[128 * 32];
  const int tid = threadIdx.x;
  const int lane = tid & 63;
  const int wave = tid >> 6;
  const int wr = wave >> 1, wc = wave & 1;
  const int m0 = blockIdx.y * 128, n0 = blockIdx.x * 128;
  const int srow = tid >> 2;
  const int scol = (tid & 3) << 3;
  f32x4 acc[4][4];
#pragma unroll
  for (int i = 0; i < 4; ++i)
#pragma unroll
    for (int j = 0; j < 4; ++j) acc[i][j] = (f32x4){0.f, 0.f, 0.f, 0.f};

  const int l15 = lane & 15, l16 = lane >> 4;
  const int aoff0 = (wr * 64 + l15) * 32 + l16 * 8;
  const int boff0 = (wc * 64 + l15) * 32 + l16 * 8;

  for (int k0 = 0; k0 < K; k0 += 32) {
    const short* gA = (const short*)&A[(size_t)(m0 + srow) * K + k0 + scol];
    const short* gB = (const short*)&Bm[(size_t)(n0 + srow) * K + k0 + scol];
    __builtin_amdgcn_global_load_lds(
        (const __attribute__((address_space(1))) unsigned int*)gA,
        (__attribute__((address_space(3))) unsigned int*)&As[tid * 8], 16, 0, 0);
    __builtin_amdgcn_global_load_lds(
        (const __attribute__((address_space(1))) unsigned int*)(gA + (size_t)64 * K),
        (__attribute__((address_space(3))) unsigned int*)&As[2048 + tid * 8], 16, 0, 0);
    __builtin_amdgcn_global_load_lds(
        (const __attribute__((address_space(1))) unsigned int*)gB,
        (__attribute__((address_space(3))) unsigned int*)&Bs[tid * 8], 16, 0, 0);
    __builtin_amdgcn_global_load_lds(
        (const __attribute__((address_space(1))) unsigned int*)(gB + (size_t)64 * K),
        (__attribute__((address_space(3))) unsigned int*)&Bs[2048 + tid * 8], 16, 0, 0);
    __syncthreads();
    bf16x8 af[4], bfr[4];
#pragma unroll
    for (int f = 0; f < 4; ++f)
      af[f] = *reinterpret_cast<const bf16x8*>(&As[aoff0 + f * 16 * 32]);
#pragma unroll
    for (int f = 0; f < 4; ++f)
      bfr[f] = *reinterpret_cast<const bf16x8*>(&Bs[boff0 + f * 16 * 32]);
#pragma unroll
    for (int m = 0; m < 4; ++m)
#pragma unroll
      for (int n = 0; n < 4; ++n)
        acc[m][n] = __builtin_amdgcn_mfma_f32_16x16x32_bf16(af[m], bfr[n], acc[m][n], 0, 0, 0);
    __syncthreads();
  }

  const int rbase = l16 * 4;
#pragma unroll
  for (int m = 0; m < 4; ++m) {
#pragma unroll
    for (int n = 0; n < 4; ++n) {
      const int col = n0 + wc * 64 + n * 16 + l15;
      const float bv = bias[col];
#pragma unroll
      for (int j = 0; j < 4; ++j) {
        const int row = m0 + wr * 64 + m * 16 + rbase + j;
        O[(size_t)row * 1024 + col] = acc[m][n][j] + bv;
      }
    }
  }
}

// ---------------------------------------------------------------------------
// Kernel B: per-(bh,chunk) KV-state via MFMA with ones-column trick.
// ---------------------------------------------------------------------------
__global__ __launch_bounds__(128) void k_chunkB(
    const unsigned short* __restrict__ Kb, const unsigned short* __restrict__ Vb,
    float* __restrict__ ST, unsigned short* __restrict__ Vtb) {
  __shared__ __align__(16) unsigned short Kt[64 * 72];  // (d, l)
  __shared__ __align__(16) unsigned short Vt[64 * 72];  // (e, l)
  const int tid = threadIdx.x;
  const int lane = tid & 63, w = tid >> 6;
  const int c = lane & 15, g = lane >> 4;
  const int bid = blockIdx.x;
  const int bh = bid >> 5, ch = bid & 31;
  const size_t base = ((size_t)bh * L_ + (size_t)ch * CHUNK) * D_;
  const int l = tid >> 1, hf = tid & 1;
  bf16x8 kv[4], vv[4];
#pragma unroll
  for (int i = 0; i < 4; ++i) {
    kv[i] = *reinterpret_cast<const bf16x8*>(&Kb[base + (size_t)l * 64 + hf * 32 + i * 8]);
    vv[i] = *reinterpret_cast<const bf16x8*>(&Vb[base + (size_t)l * 64 + hf * 32 + i * 8]);
  }
#pragma unroll
  for (int i = 0; i < 4; ++i)
#pragma unroll
    for (int r = 0; r < 8; ++r) {
      const int d = hf * 32 + i * 8 + r;
      Kt[d * 72 + l] = (unsigned short)kv[i][r];
      Vt[d * 72 + l] = (unsigned short)vv[i][r];
    }
  __syncthreads();
  bf16x8 kf[4][2], vf[2][2];
#pragma unroll
  for (int dt = 0; dt < 4; ++dt)
#pragma unroll
    for (int kh = 0; kh < 2; ++kh)
      kf[dt][kh] = *reinterpret_cast<const bf16x8*>(&Kt[(dt * 16 + c) * 72 + g * 8 + kh * 32]);
#pragma unroll
  for (int ei = 0; ei < 2; ++ei)
#pragma unroll
    for (int kh = 0; kh < 2; ++kh)
      vf[ei][kh] = *reinterpret_cast<const bf16x8*>(&Vt[((w * 2 + ei) * 16 + c) * 72 + g * 8 + kh * 32]);
  f32x4 acc[2][4];
#pragma unroll
  for (int ei = 0; ei < 2; ++ei)
#pragma unroll
    for (int dt = 0; dt < 4; ++dt) acc[ei][dt] = (f32x4){0.f, 0.f, 0.f, 0.f};
#pragma unroll
  for (int ei = 0; ei < 2; ++ei)
#pragma unroll
    for (int dt = 0; dt < 4; ++dt)
#pragma unroll
      for (int kh = 0; kh < 2; ++kh)
        acc[ei][dt] = __builtin_amdgcn_mfma_f32_16x16x32_bf16(vf[ei][kh], kf[dt][kh], acc[ei][dt], 0, 0, 0);
  const size_t stbase = (size_t)bid * 5120;
#pragma unroll
  for (int ei = 0; ei < 2; ++ei)
#pragma unroll
    for (int dt = 0; dt < 4; ++dt)
#pragma unroll
      for (int r = 0; r < 4; ++r)
        ST[stbase + (size_t)((w * 2 + ei) * 16 + 4 * g + r) * 64 + dt * 16 + c] = acc[ei][dt][r];
#pragma unroll
  for (int ei = 0; ei < 2; ++ei)
#pragma unroll
    for (int kh = 0; kh < 2; ++kh)
      *reinterpret_cast<bf16x8*>(&Vtb[(size_t)bid * 4096 + ((w * 2 + ei) * 16 + c) * 64 + g * 8 + kh * 32]) = vf[ei][kh];
  if (w == 0) {
    const short one = (c == 0) ? (short)0x3F80 : (short)0;
    bf16x8 of;
#pragma unroll
    for (int r = 0; r < 8; ++r) of[r] = one;
    f32x4 az[4];
#pragma unroll
    for (int dt = 0; dt < 4; ++dt) az[dt] = (f32x4){0.f, 0.f, 0.f, 0.f};
#pragma unroll
    for (int dt = 0; dt < 4; ++dt)
#pragma unroll
      for (int kh = 0; kh < 2; ++kh)
        az[dt] = __builtin_amdgcn_mfma_f32_16x16x32_bf16(of, kf[dt][kh], az[dt], 0, 0, 0);
    if (g == 0) {
#pragma unroll
      for (int dt = 0; dt < 4; ++dt)
        ST[stbase + 64 * 64 + dt * 16 + c] = az[dt][0];
    }
  }
}

// ---------------------------------------------------------------------------
// Kernel C: element-parallel exclusive prefix over 32 chunks per (bh).
// ---------------------------------------------------------------------------
__global__ __launch_bounds__(256) void k_prefix2(const float* __restrict__ ST,
                                                 unsigned short* __restrict__ STb) {
  const int bh = blockIdx.x;
  const int e = blockIdx.y * 256 + threadIdx.x;
  if (e >= 4160) return;
  const size_t base = (size_t)bh * NCHUNK * 5120 + e;
  float run = 0.f;
  for (int cc = 0; cc < NCHUNK; ++cc) {
    const float t = ST[base + (size_t)cc * 5120];
    STb[base + (size_t)cc * 5120] = f2bf(run);
    run += t;
  }
}

// ---------------------------------------------------------------------------
// Kernel D: per-(bh,chunk) output via MFMA (swapped QK^T + ones-column den).
// ---------------------------------------------------------------------------
__global__ __launch_bounds__(256) void k_chunkD(
    const unsigned short* __restrict__ Qb, const unsigned short* __restrict__ Kb,
    const unsigned short* __restrict__ Vtb, const unsigned short* __restrict__ STb,
    unsigned short* __restrict__ attnb) {
  __shared__ __align__(16) unsigned short P[4][1024];
  const int tid = threadIdx.x;
  const int lane = tid & 63, lt = tid >> 6;
  const int c = lane & 15, g = lane >> 4;
  const int bid = blockIdx.x;
  const int bh = bid >> 5, ch = bid & 31;
  const int b = bh >> 4, h = bh & 15;
  const size_t qkbase = ((size_t)bh * L_ + (size_t)ch * CHUNK) * D_;
  bf16x8 q[2], k4[4][2], s[5][2], vt[4][2], pa[2];
#pragma unroll
  for (int kh = 0; kh < 2; ++kh)
    q[kh] = *reinterpret_cast<const bf16x8*>(&Qb[qkbase + (size_t)(lt * 16 + c) * 64 + g * 8 + kh * 32]);
#pragma unroll
  for (int jt = 0; jt < 4; ++jt)
#pragma unroll
    for (int kh = 0; kh < 2; ++kh)
      k4[jt][kh] = *reinterpret_cast<const bf16x8*>(&Kb[qkbase + (size_t)(jt * 16 + c) * 64 + g * 8 + kh * 32]);
  const size_t stbase = (size_t)bid * 5120;
#pragma unroll
  for (int et = 0; et < 5; ++et)
#pragma unroll
    for (int kh = 0; kh < 2; ++kh)
      s[et][kh] = *reinterpret_cast<const bf16x8*>(&STb[stbase + (size_t)(et * 16 + c) * 64 + g * 8 + kh * 32]);
#pragma unroll
  for (int et = 0; et < 4; ++et)
#pragma unroll
    for (int kh = 0; kh < 2; ++kh)
      vt[et][kh] = *reinterpret_cast<const bf16x8*>(&Vtb[(size_t)bid * 4096 + (size_t)(et * 16 + c) * 64 + g * 8 + kh * 32]);

  char* Pb = (char*)&P[lt][0];
  const int swz = (c & 7) << 4;
#pragma unroll
  for (int jt = 0; jt < 4; ++jt) {
    unsigned pk0 = 0, pk1 = 0;
    if (jt <= lt) {
      f32x4 a1 = (f32x4){0.f, 0.f, 0.f, 0.f};
#pragma unroll
      for (int kh = 0; kh < 2; ++kh)
        a1 = __builtin_amdgcn_mfma_f32_16x16x32_bf16(k4[jt][kh], q[kh], a1, 0, 0, 0);
      if (jt == lt) {
#pragma unroll
        for (int r = 0; r < 4; ++r) a1[r] = (4 * g + r <= c) ? a1[r] : 0.f;
      }
      pk0 = (unsigned)f2bf(a1[0]) | ((unsigned)f2bf(a1[1]) << 16);
      pk1 = (unsigned)f2bf(a1[2]) | ((unsigned)f2bf(a1[3]) << 16);
    }
    *reinterpret_cast<unsigned*>(Pb + ((c * 128 + 32 * jt + 8 * g + 0) ^ swz)) = pk0;
    *reinterpret_cast<unsigned*>(Pb + ((c * 128 + 32 * jt + 8 * g + 4) ^ swz)) = pk1;
  }
#pragma unroll
  for (int kh = 0; kh < 2; ++kh)
    pa[kh] = *reinterpret_cast<const bf16x8*>(Pb + (c * 128 + ((16 * g + 64 * kh) ^ swz)));

  f32x4 acc2[5];
#pragma unroll
  for (int et = 0; et < 5; ++et) acc2[et] = (f32x4){0.f, 0.f, 0.f, 0.f};
  const short one = (c == 0) ? (short)0x3F80 : (short)0;
  bf16x8 of;
#pragma unroll
  for (int r = 0; r < 8; ++r) of[r] = one;
#pragma unroll
  for (int et = 0; et < 5; ++et) {
#pragma unroll
    for (int kh = 0; kh < 2; ++kh) {
      acc2[et] = __builtin_amdgcn_mfma_f32_16x16x32_bf16(q[kh], s[et][kh], acc2[et], 0, 0, 0);
      bf16x8 vv = (et < 4) ? vt[et][kh] : of;
      acc2[et] = __builtin_amdgcn_mfma_f32_16x16x32_bf16(pa[kh], vv, acc2[et], 0, 0, 0);
    }
  }
  float inv[4];
#pragma unroll
  for (int r = 0; r < 4; ++r) {
    float dv = __shfl(acc2[4][r], lane & 48, 64);
    inv[r] = 1.f / fmaxf(dv, 1e-6f);
  }
  const size_t obase = ((size_t)b * L_ + (size_t)ch * CHUNK + (size_t)lt * 16) * E_ + (size_t)h * 64;
#pragma unroll
  for (int et = 0; et < 4; ++et)
#pragma unroll
    for (int r = 0; r < 4; ++r)
      attnb[obase + (size_t)(4 * g + r) * E_ + et * 16 + c] = f2bf(acc2[et][r] * inv[r]);
}

// ---------------------------------------------------------------------------
extern "C" void kernel_launch(void* const* d_in, const int* in_sizes, int n_in,
                              void* d_out, int out_size, void* d_ws, size_t ws_size,
                              hipStream_t stream) {
  const float* x = (const float*)d_in[0];
  const float* qkv_w = (const float*)d_in[1];
  const float* qkv_b = (const float*)d_in[2];
  const float* out_w = (const float*)d_in[3];
  const float* out_b = (const float*)d_in[4];
  float* out = (float*)d_out;

  const size_t SZ = (size_t)B_ * H_ * L_ * D_;  // 4,194,304
  char* p = (char*)d_ws;
  unsigned short* Qb = (unsigned short*)p;    p += SZ * 2;
  unsigned short* Kb = (unsigned short*)p;    p += SZ * 2;
  unsigned short* Vb = (unsigned short*)p;    p += SZ * 2;
  unsigned short* Vtb = (unsigned short*)p;   p += (size_t)1024 * 4096 * 2;
  float* ST = (float*)p;                      p += (size_t)1024 * 5120 * 4;
  unsigned short* STb = (unsigned short*)p;   p += (size_t)1024 * 5120 * 2;
  unsigned short* xb = (unsigned short*)p;    p += SZ * 2;
  unsigned short* wqkv = (unsigned short*)p;  p += (size_t)N3_ * E_ * 2;
  unsigned short* wout = (unsigned short*)p;  p += (size_t)E_ * E_ * 2;
  unsigned short* attnb = (unsigned short*)p; p += SZ * 2;

  dim3 blk(256);
  // fp32 -> bf16 converts (one kernel, 2097152 float4s)
  k_cvt_all<<<dim3(8192), blk, 0, stream>>>(x, qkv_w, out_w, xb, wqkv, wout);
  // QKV projection (M=4096, N=3072, K=1024), 256x192 8-phase, grid=256
  k_gemm256_qkv<<<dim3(16, 16), dim3(512), 0, stream>>>(xb, wqkv, qkv_b, Qb, Kb, Vb);
  // chunked scan, MFMA
  k_chunkB<<<dim3(1024), dim3(128), 0, stream>>>(Kb, Vb, ST, Vtb);
  k_prefix2<<<dim3(32, 17), blk, 0, stream>>>(ST, STb);
  k_chunkD<<<dim3(1024), blk, 0, stream>>>(Qb, Kb, Vtb, STb, attnb);
  // output projection (M=4096, N=1024, K=1024), m97 structure
  k_gemm_out<<<dim3(E_ / 128, (B_ * L_) / 128), blk, 0, stream>>>(
      attnb, wout, out_b, out, E_);
}

// Round 7
// 163.620 us; speedup vs baseline: 4.0424x; 1.0609x over previous
//
#include <hip/hip_runtime.h>
#include <hip/hip_bf16.h>
#include <cstdint>

// Problem constants
#define B_ 2
#define L_ 2048
#define E_ 1024
#define H_ 16
#define D_ 64
#define N3_ 3072
#define NCHUNK 32
#define CHUNK 64

typedef __attribute__((ext_vector_type(8))) short bf16x8;
typedef __attribute__((ext_vector_type(4))) float f32x4;

__device__ __forceinline__ unsigned short f2bf(float f) {
  unsigned u = __float_as_uint(f);
  unsigned r = (u + 0x7fffu + ((u >> 16) & 1u)) >> 16;  // RNE
  return (unsigned short)r;
}
__device__ __forceinline__ float bf2f(unsigned short u) {
  return __uint_as_float(((unsigned)u) << 16);
}

// ---------------------------------------------------------------------------
// fp32 -> bf16 conversion, all three tensors in one launch.
// ranges (float4 units): x 1048576 | qkv_w 786432 | out_w 262144
// ---------------------------------------------------------------------------
__global__ __launch_bounds__(256) void k_cvt_all(
    const float* __restrict__ x, const float* __restrict__ qkv_w,
    const float* __restrict__ out_w, unsigned short* __restrict__ xb,
    unsigned short* __restrict__ wqkv, unsigned short* __restrict__ wout) {
  const int i = blockIdx.x * 256 + threadIdx.x;
  const float* src;
  unsigned short* dst;
  int j;
  if (i < 1048576)      { src = x;     dst = xb;   j = i; }
  else if (i < 1835008) { src = qkv_w; dst = wqkv; j = i - 1048576; }
  else                  { src = out_w; dst = wout; j = i - 1835008; }
  float4 v = reinterpret_cast<const float4*>(src)[j];
  ushort4 o;
  o.x = f2bf(v.x); o.y = f2bf(v.y); o.z = f2bf(v.z); o.w = f2bf(v.w);
  reinterpret_cast<ushort4*>(dst)[j] = o;
}

// ---------------------------------------------------------------------------
// QKV GEMM: 256x192 tile, BK=64, 8 waves (2M x 4N, wave tile 128x48),
// 8-phase schedule, counted vmcnt, LDS XOR-swizzle, setprio, XCD swizzle.
// Grid 16x16 = 256 blocks = exactly 1/CU.
// ---------------------------------------------------------------------------
__global__ __launch_bounds__(512, 2) void k_gemm256_qkv(
    const unsigned short* __restrict__ A,   // (4096,1024) bf16
    const unsigned short* __restrict__ Bm,  // (3072,1024) bf16
    const float* __restrict__ bias,
    unsigned short* __restrict__ Qb, unsigned short* __restrict__ Kb,
    unsigned short* __restrict__ Vb) {
  __shared__ short As[2][256 * 64];
  __shared__ short Bs[2][192 * 64];
  const int tid = threadIdx.x;
  const int lane = tid & 63, wave = tid >> 6;
  const int wm = wave >> 2, wn = wave & 3;
  const int bid0 = blockIdx.y * 16 + blockIdx.x;
  const int bid = (bid0 & 7) * 32 + (bid0 >> 3);  // bijective XCD swizzle
  const int m0 = (bid >> 4) * 256, n0 = (bid & 15) * 192;
  const int srow = tid >> 3, scol = (tid & 7) * 8;
  const int ssw = (srow & 7) * 8;
  const int l15 = lane & 15, l16 = lane >> 4;
  const int sw = (l15 & 7) * 8;
  const int NT = 16;

  f32x4 acc[8][3];
#pragma unroll
  for (int i = 0; i < 8; ++i)
#pragma unroll
    for (int j = 0; j < 3; ++j) acc[i][j] = (f32x4){0.f, 0.f, 0.f, 0.f};

  auto stageA = [&](int d, int kt) {  // 4 insts
#pragma unroll
    for (int i = 0; i < 4; ++i) {
      const int r = i * 64 + srow;
      const unsigned short* src = &A[(size_t)(m0 + r) * 1024 + kt * 64 + (scol ^ ssw)];
      __builtin_amdgcn_global_load_lds(
          (const __attribute__((address_space(1))) unsigned int*)src,
          (__attribute__((address_space(3))) unsigned int*)&As[d][r * 64 + scol], 16, 0, 0);
    }
  };
  auto stageB = [&](int d, int kt) {  // 3 insts
#pragma unroll
    for (int i = 0; i < 3; ++i) {
      const int r = i * 64 + srow;
      const unsigned short* src = &Bm[(size_t)(n0 + r) * 1024 + kt * 64 + (scol ^ ssw)];
      __builtin_amdgcn_global_load_lds(
          (const __attribute__((address_space(1))) unsigned int*)src,
          (__attribute__((address_space(3))) unsigned int*)&Bs[d][r * 64 + scol], 16, 0, 0);
    }
  };
  auto lda = [&](bf16x8 (&dv)[8], int d, int kh) {
#pragma unroll
    for (int mi = 0; mi < 8; ++mi) {
      const int r = wm * 128 + mi * 16 + l15;
      dv[mi] = *reinterpret_cast<const bf16x8*>(&As[d][r * 64 + ((l16 * 8 + kh * 32) ^ sw)]);
    }
  };
  auto ldb = [&](bf16x8 (&dv)[3], int d, int kh) {
#pragma unroll
    for (int ni = 0; ni < 3; ++ni) {
      const int r = wn * 48 + ni * 16 + l15;
      dv[ni] = *reinterpret_cast<const bf16x8*>(&Bs[d][r * 64 + ((l16 * 8 + kh * 32) ^ sw)]);
    }
  };
  auto quad = [&](const bf16x8 (&af)[8], const bf16x8 (&bf)[3], int nb, int ne) {
    __builtin_amdgcn_s_setprio(1);
#pragma unroll
    for (int mi = 0; mi < 8; ++mi)
      for (int nn = nb; nn < ne; ++nn)
        acc[mi][nn] = __builtin_amdgcn_mfma_f32_16x16x32_bf16(af[mi], bf[nn], acc[mi][nn], 0, 0, 0);
    __builtin_amdgcn_s_setprio(0);
  };

  stageA(0, 0); stageB(0, 0); stageA(1, 1);
  asm volatile("s_waitcnt vmcnt(4)" ::: "memory");
  __builtin_amdgcn_s_barrier();

  bf16x8 af0[8], af1[8], bf0[3], bf1[3];
  for (int t = 0; t < NT; ++t) {
    const int d = t & 1;
    lda(af0, d, 0); ldb(bf0, d, 0);
    if (t + 1 < NT) stageB(d ^ 1, t + 1);
    __builtin_amdgcn_s_barrier();
    asm volatile("s_waitcnt lgkmcnt(0)" ::: "memory");
    __builtin_amdgcn_sched_barrier(0);
    quad(af0, bf0, 0, 2);
    __builtin_amdgcn_s_barrier();
    lda(af1, d, 1); ldb(bf1, d, 1);
    __builtin_amdgcn_s_barrier();
    asm volatile("s_waitcnt lgkmcnt(0)" ::: "memory");
    __builtin_amdgcn_sched_barrier(0);
    quad(af0, bf0, 2, 3);
    __builtin_amdgcn_s_barrier();
    if (t + 2 < NT) stageA(d, t + 2);
    quad(af1, bf1, 0, 2);
    __builtin_amdgcn_s_barrier();
    quad(af1, bf1, 2, 3);
    if (t + 2 < NT) asm volatile("s_waitcnt vmcnt(4)" ::: "memory");
    else            asm volatile("s_waitcnt vmcnt(0)" ::: "memory");
    __builtin_amdgcn_s_barrier();
  }

#pragma unroll
  for (int mi = 0; mi < 8; ++mi) {
#pragma unroll
    for (int ni = 0; ni < 3; ++ni) {
      const int col = n0 + wn * 48 + ni * 16 + l15;
      const float bv = bias[col];
      const int t = col >> 10, hd = col & 1023;
      const int h = hd >> 6, dd = hd & 63;
#pragma unroll
      for (int j = 0; j < 4; ++j) {
        const int row = m0 + wm * 128 + mi * 16 + l16 * 4 + j;
        const float val = acc[mi][ni][j] + bv;
        const int b = row >> 11, l = row & 2047;
        const size_t dst = (((size_t)(b * 16 + h)) * 2048 + l) * 64 + dd;
        if (t == 0)      Qb[dst] = f2bf(fmaxf(val, 0.f) + 1e-6f);
        else if (t == 1) Kb[dst] = f2bf(fmaxf(val, 0.f) + 1e-6f);
        else             Vb[dst] = f2bf(val);
      }
    }
  }
}

// ---------------------------------------------------------------------------
// Output GEMM: 256x64 tile, BK=64, 8 waves (2M x 4N, wave tile 128x16),
// same 8-phase template (parameter port of k_gemm256_qkv).
// Ledger: per tile B(t+1)x1 @ph1, A(t+2)x4 @ph3, vmcnt(4) @ph4.
// LDS 80KB -> 2 blocks/CU. Grid 16x16 = 256 blocks.
// ---------------------------------------------------------------------------
__global__ __launch_bounds__(512, 2) void k_gemm256_out(
    const unsigned short* __restrict__ A,   // attn (4096,1024) bf16
    const unsigned short* __restrict__ Bm,  // out_w (1024,1024) bf16
    const float* __restrict__ bias, float* __restrict__ O) {
  __shared__ short As[2][256 * 64];
  __shared__ short Bs[2][64 * 64];
  const int tid = threadIdx.x;
  const int lane = tid & 63, wave = tid >> 6;
  const int wm = wave >> 2, wn = wave & 3;
  const int bid0 = blockIdx.y * 16 + blockIdx.x;
  const int bid = (bid0 & 7) * 32 + (bid0 >> 3);  // bijective XCD swizzle
  const int m0 = (bid >> 4) * 256, n0 = (bid & 15) * 64;
  const int srow = tid >> 3, scol = (tid & 7) * 8;
  const int ssw = (srow & 7) * 8;
  const int l15 = lane & 15, l16 = lane >> 4;
  const int sw = (l15 & 7) * 8;
  const int NT = 16;

  f32x4 acc[8];
#pragma unroll
  for (int i = 0; i < 8; ++i) acc[i] = (f32x4){0.f, 0.f, 0.f, 0.f};

  auto stageA = [&](int d, int kt) {  // 4 insts
#pragma unroll
    for (int i = 0; i < 4; ++i) {
      const int r = i * 64 + srow;
      const unsigned short* src = &A[(size_t)(m0 + r) * 1024 + kt * 64 + (scol ^ ssw)];
      __builtin_amdgcn_global_load_lds(
          (const __attribute__((address_space(1))) unsigned int*)src,
          (__attribute__((address_space(3))) unsigned int*)&As[d][r * 64 + scol], 16, 0, 0);
    }
  };
  auto stageB = [&](int d, int kt) {  // 1 inst
    const unsigned short* src = &Bm[(size_t)(n0 + srow) * 1024 + kt * 64 + (scol ^ ssw)];
    __builtin_amdgcn_global_load_lds(
        (const __attribute__((address_space(1))) unsigned int*)src,
        (__attribute__((address_space(3))) unsigned int*)&Bs[d][srow * 64 + scol], 16, 0, 0);
  };
  auto lda = [&](bf16x8 (&dv)[8], int d, int kh) {
#pragma unroll
    for (int mi = 0; mi < 8; ++mi) {
      const int r = wm * 128 + mi * 16 + l15;
      dv[mi] = *reinterpret_cast<const bf16x8*>(&As[d][r * 64 + ((l16 * 8 + kh * 32) ^ sw)]);
    }
  };
  auto ldb = [&](bf16x8& dv, int d, int kh) {
    const int r = wn * 16 + l15;
    dv = *reinterpret_cast<const bf16x8*>(&Bs[d][r * 64 + ((l16 * 8 + kh * 32) ^ sw)]);
  };
  auto half = [&](const bf16x8 (&af)[8], const bf16x8& bf, int mb) {
    __builtin_amdgcn_s_setprio(1);
#pragma unroll
    for (int mi = mb; mi < mb + 4; ++mi)
      acc[mi] = __builtin_amdgcn_mfma_f32_16x16x32_bf16(af[mi], bf, acc[mi], 0, 0, 0);
    __builtin_amdgcn_s_setprio(0);
  };

  stageA(0, 0); stageB(0, 0); stageA(1, 1);
  asm volatile("s_waitcnt vmcnt(4)" ::: "memory");
  __builtin_amdgcn_s_barrier();

  bf16x8 af0[8], af1[8], bf0, bf1;
  for (int t = 0; t < NT; ++t) {
    const int d = t & 1;
    lda(af0, d, 0); ldb(bf0, d, 0);
    if (t + 1 < NT) stageB(d ^ 1, t + 1);
    __builtin_amdgcn_s_barrier();
    asm volatile("s_waitcnt lgkmcnt(0)" ::: "memory");
    __builtin_amdgcn_sched_barrier(0);
    half(af0, bf0, 0);
    __builtin_amdgcn_s_barrier();
    lda(af1, d, 1); ldb(bf1, d, 1);
    __builtin_amdgcn_s_barrier();
    asm volatile("s_waitcnt lgkmcnt(0)" ::: "memory");
    __builtin_amdgcn_sched_barrier(0);
    half(af0, bf0, 4);
    __builtin_amdgcn_s_barrier();
    if (t + 2 < NT) stageA(d, t + 2);
    half(af1, bf1, 0);
    __builtin_amdgcn_s_barrier();
    half(af1, bf1, 4);
    if (t + 2 < NT) asm volatile("s_waitcnt vmcnt(4)" ::: "memory");
    else            asm volatile("s_waitcnt vmcnt(0)" ::: "memory");
    __builtin_amdgcn_s_barrier();
  }

  const int col = n0 + wn * 16 + l15;
  const float bv = bias[col];
#pragma unroll
  for (int mi = 0; mi < 8; ++mi) {
#pragma unroll
    for (int j = 0; j < 4; ++j) {
      const int row = m0 + wm * 128 + mi * 16 + l16 * 4 + j;
      O[(size_t)row * 1024 + col] = acc[mi][j] + bv;
    }
  }
}

// ---------------------------------------------------------------------------
// Kernel B: per-(bh,chunk) KV-state via MFMA with ones-column trick.
// Chunk sums now stored bf16 (STc); prefix accumulates fp32 from bf16.
// ---------------------------------------------------------------------------
__global__ __launch_bounds__(128) void k_chunkB(
    const unsigned short* __restrict__ Kb, const unsigned short* __restrict__ Vb,
    unsigned short* __restrict__ STc, unsigned short* __restrict__ Vtb) {
  __shared__ __align__(16) unsigned short Kt[64 * 72];  // (d, l)
  __shared__ __align__(16) unsigned short Vt[64 * 72];  // (e, l)
  const int tid = threadIdx.x;
  const int lane = tid & 63, w = tid >> 6;
  const int c = lane & 15, g = lane >> 4;
  const int bid = blockIdx.x;
  const int bh = bid >> 5, ch = bid & 31;
  const size_t base = ((size_t)bh * L_ + (size_t)ch * CHUNK) * D_;
  const int l = tid >> 1, hf = tid & 1;
  bf16x8 kv[4], vv[4];
#pragma unroll
  for (int i = 0; i < 4; ++i) {
    kv[i] = *reinterpret_cast<const bf16x8*>(&Kb[base + (size_t)l * 64 + hf * 32 + i * 8]);
    vv[i] = *reinterpret_cast<const bf16x8*>(&Vb[base + (size_t)l * 64 + hf * 32 + i * 8]);
  }
#pragma unroll
  for (int i = 0; i < 4; ++i)
#pragma unroll
    for (int r = 0; r < 8; ++r) {
      const int d = hf * 32 + i * 8 + r;
      Kt[d * 72 + l] = (unsigned short)kv[i][r];
      Vt[d * 72 + l] = (unsigned short)vv[i][r];
    }
  __syncthreads();
  bf16x8 kf[4][2], vf[2][2];
#pragma unroll
  for (int dt = 0; dt < 4; ++dt)
#pragma unroll
    for (int kh = 0; kh < 2; ++kh)
      kf[dt][kh] = *reinterpret_cast<const bf16x8*>(&Kt[(dt * 16 + c) * 72 + g * 8 + kh * 32]);
#pragma unroll
  for (int ei = 0; ei < 2; ++ei)
#pragma unroll
    for (int kh = 0; kh < 2; ++kh)
      vf[ei][kh] = *reinterpret_cast<const bf16x8*>(&Vt[((w * 2 + ei) * 16 + c) * 72 + g * 8 + kh * 32]);
  f32x4 acc[2][4];
#pragma unroll
  for (int ei = 0; ei < 2; ++ei)
#pragma unroll
    for (int dt = 0; dt < 4; ++dt) acc[ei][dt] = (f32x4){0.f, 0.f, 0.f, 0.f};
#pragma unroll
  for (int ei = 0; ei < 2; ++ei)
#pragma unroll
    for (int dt = 0; dt < 4; ++dt)
#pragma unroll
      for (int kh = 0; kh < 2; ++kh)
        acc[ei][dt] = __builtin_amdgcn_mfma_f32_16x16x32_bf16(vf[ei][kh], kf[dt][kh], acc[ei][dt], 0, 0, 0);
  const size_t stbase = (size_t)bid * 5120;
#pragma unroll
  for (int ei = 0; ei < 2; ++ei)
#pragma unroll
    for (int dt = 0; dt < 4; ++dt)
#pragma unroll
      for (int r = 0; r < 4; ++r)
        STc[stbase + (size_t)((w * 2 + ei) * 16 + 4 * g + r) * 64 + dt * 16 + c] = f2bf(acc[ei][dt][r]);
#pragma unroll
  for (int ei = 0; ei < 2; ++ei)
#pragma unroll
    for (int kh = 0; kh < 2; ++kh)
      *reinterpret_cast<bf16x8*>(&Vtb[(size_t)bid * 4096 + ((w * 2 + ei) * 16 + c) * 64 + g * 8 + kh * 32]) = vf[ei][kh];
  if (w == 0) {
    const short one = (c == 0) ? (short)0x3F80 : (short)0;
    bf16x8 of;
#pragma unroll
    for (int r = 0; r < 8; ++r) of[r] = one;
    f32x4 az[4];
#pragma unroll
    for (int dt = 0; dt < 4; ++dt) az[dt] = (f32x4){0.f, 0.f, 0.f, 0.f};
#pragma unroll
    for (int dt = 0; dt < 4; ++dt)
#pragma unroll
      for (int kh = 0; kh < 2; ++kh)
        az[dt] = __builtin_amdgcn_mfma_f32_16x16x32_bf16(of, kf[dt][kh], az[dt], 0, 0, 0);
    if (g == 0) {
#pragma unroll
      for (int dt = 0; dt < 4; ++dt)
        STc[stbase + 64 * 64 + dt * 16 + c] = f2bf(az[dt][0]);
    }
  }
}

// ---------------------------------------------------------------------------
// Kernel C: element-parallel exclusive prefix over 32 chunks per (bh).
// Reads bf16 chunk sums, accumulates fp32, writes bf16 prefix.
// ---------------------------------------------------------------------------
__global__ __launch_bounds__(256) void k_prefix2(const unsigned short* __restrict__ STc,
                                                 unsigned short* __restrict__ STb) {
  const int bh = blockIdx.x;
  const int e = blockIdx.y * 256 + threadIdx.x;
  if (e >= 4160) return;
  const size_t base = (size_t)bh * NCHUNK * 5120 + e;
  float run = 0.f;
  for (int cc = 0; cc < NCHUNK; ++cc) {
    const float t = bf2f(STc[base + (size_t)cc * 5120]);
    STb[base + (size_t)cc * 5120] = f2bf(run);
    run += t;
  }
}

// ---------------------------------------------------------------------------
// Kernel D: per-(bh,chunk) output via MFMA (swapped QK^T + ones-column den).
// ---------------------------------------------------------------------------
__global__ __launch_bounds__(256) void k_chunkD(
    const unsigned short* __restrict__ Qb, const unsigned short* __restrict__ Kb,
    const unsigned short* __restrict__ Vtb, const unsigned short* __restrict__ STb,
    unsigned short* __restrict__ attnb) {
  __shared__ __align__(16) unsigned short P[4][1024];
  const int tid = threadIdx.x;
  const int lane = tid & 63, lt = tid >> 6;
  const int c = lane & 15, g = lane >> 4;
  const int bid = blockIdx.x;
  const int bh = bid >> 5, ch = bid & 31;
  const int b = bh >> 4, h = bh & 15;
  const size_t qkbase = ((size_t)bh * L_ + (size_t)ch * CHUNK) * D_;
  bf16x8 q[2], k4[4][2], s[5][2], vt[4][2], pa[2];
#pragma unroll
  for (int kh = 0; kh < 2; ++kh)
    q[kh] = *reinterpret_cast<const bf16x8*>(&Qb[qkbase + (size_t)(lt * 16 + c) * 64 + g * 8 + kh * 32]);
#pragma unroll
  for (int jt = 0; jt < 4; ++jt)
#pragma unroll
    for (int kh = 0; kh < 2; ++kh)
      k4[jt][kh] = *reinterpret_cast<const bf16x8*>(&Kb[qkbase + (size_t)(jt * 16 + c) * 64 + g * 8 + kh * 32]);
  const size_t stbase = (size_t)bid * 5120;
#pragma unroll
  for (int et = 0; et < 5; ++et)
#pragma unroll
    for (int kh = 0; kh < 2; ++kh)
      s[et][kh] = *reinterpret_cast<const bf16x8*>(&STb[stbase + (size_t)(et * 16 + c) * 64 + g * 8 + kh * 32]);
#pragma unroll
  for (int et = 0; et < 4; ++et)
#pragma unroll
    for (int kh = 0; kh < 2; ++kh)
      vt[et][kh] = *reinterpret_cast<const bf16x8*>(&Vtb[(size_t)bid * 4096 + (size_t)(et * 16 + c) * 64 + g * 8 + kh * 32]);

  char* Pb = (char*)&P[lt][0];
  const int swz = (c & 7) << 4;
#pragma unroll
  for (int jt = 0; jt < 4; ++jt) {
    unsigned pk0 = 0, pk1 = 0;
    if (jt <= lt) {
      f32x4 a1 = (f32x4){0.f, 0.f, 0.f, 0.f};
#pragma unroll
      for (int kh = 0; kh < 2; ++kh)
        a1 = __builtin_amdgcn_mfma_f32_16x16x32_bf16(k4[jt][kh], q[kh], a1, 0, 0, 0);
      if (jt == lt) {
#pragma unroll
        for (int r = 0; r < 4; ++r) a1[r] = (4 * g + r <= c) ? a1[r] : 0.f;
      }
      pk0 = (unsigned)f2bf(a1[0]) | ((unsigned)f2bf(a1[1]) << 16);
      pk1 = (unsigned)f2bf(a1[2]) | ((unsigned)f2bf(a1[3]) << 16);
    }
    *reinterpret_cast<unsigned*>(Pb + ((c * 128 + 32 * jt + 8 * g + 0) ^ swz)) = pk0;
    *reinterpret_cast<unsigned*>(Pb + ((c * 128 + 32 * jt + 8 * g + 4) ^ swz)) = pk1;
  }
#pragma unroll
  for (int kh = 0; kh < 2; ++kh)
    pa[kh] = *reinterpret_cast<const bf16x8*>(Pb + (c * 128 + ((16 * g + 64 * kh) ^ swz)));

  f32x4 acc2[5];
#pragma unroll
  for (int et = 0; et < 5; ++et) acc2[et] = (f32x4){0.f, 0.f, 0.f, 0.f};
  const short one = (c == 0) ? (short)0x3F80 : (short)0;
  bf16x8 of;
#pragma unroll
  for (int r = 0; r < 8; ++r) of[r] = one;
#pragma unroll
  for (int et = 0; et < 5; ++et) {
#pragma unroll
    for (int kh = 0; kh < 2; ++kh) {
      acc2[et] = __builtin_amdgcn_mfma_f32_16x16x32_bf16(q[kh], s[et][kh], acc2[et], 0, 0, 0);
      bf16x8 vv = (et < 4) ? vt[et][kh] : of;
      acc2[et] = __builtin_amdgcn_mfma_f32_16x16x32_bf16(pa[kh], vv, acc2[et], 0, 0, 0);
    }
  }
  float inv[4];
#pragma unroll
  for (int r = 0; r < 4; ++r) {
    float dv = __shfl(acc2[4][r], lane & 48, 64);
    inv[r] = 1.f / fmaxf(dv, 1e-6f);
  }
  const size_t obase = ((size_t)b * L_ + (size_t)ch * CHUNK + (size_t)lt * 16) * E_ + (size_t)h * 64;
#pragma unroll
  for (int et = 0; et < 4; ++et)
#pragma unroll
    for (int r = 0; r < 4; ++r)
      attnb[obase + (size_t)(4 * g + r) * E_ + et * 16 + c] = f2bf(acc2[et][r] * inv[r]);
}

// ---------------------------------------------------------------------------
extern "C" void kernel_launch(void* const* d_in, const int* in_sizes, int n_in,
                              void* d_out, int out_size, void* d_ws, size_t ws_size,
                              hipStream_t stream) {
  const float* x = (const float*)d_in[0];
  const float* qkv_w = (const float*)d_in[1];
  const float* qkv_b = (const float*)d_in[2];
  const float* out_w = (const float*)d_in[3];
  const float* out_b = (const float*)d_in[4];
  float* out = (float*)d_out;

  const size_t SZ = (size_t)B_ * H_ * L_ * D_;  // 4,194,304
  char* p = (char*)d_ws;
  unsigned short* Qb = (unsigned short*)p;    p += SZ * 2;
  unsigned short* Kb = (unsigned short*)p;    p += SZ * 2;
  unsigned short* Vb = (unsigned short*)p;    p += SZ * 2;
  unsigned short* Vtb = (unsigned short*)p;   p += (size_t)1024 * 4096 * 2;
  unsigned short* STc = (unsigned short*)p;   p += (size_t)1024 * 5120 * 2;
  unsigned short* STb = (unsigned short*)p;   p += (size_t)1024 * 5120 * 2;
  unsigned short* xb = (unsigned short*)p;    p += SZ * 2;
  unsigned short* wqkv = (unsigned short*)p;  p += (size_t)N3_ * E_ * 2;
  unsigned short* wout = (unsigned short*)p;  p += (size_t)E_ * E_ * 2;
  unsigned short* attnb = (unsigned short*)p; p += SZ * 2;

  dim3 blk(256);
  // fp32 -> bf16 converts (one kernel, 2097152 float4s)
  k_cvt_all<<<dim3(8192), blk, 0, stream>>>(x, qkv_w, out_w, xb, wqkv, wout);
  // QKV projection (M=4096, N=3072, K=1024), 256x192 8-phase, grid=256
  k_gemm256_qkv<<<dim3(16, 16), dim3(512), 0, stream>>>(xb, wqkv, qkv_b, Qb, Kb, Vb);
  // chunked scan, MFMA
  k_chunkB<<<dim3(1024), dim3(128), 0, stream>>>(Kb, Vb, STc, Vtb);
  k_prefix2<<<dim3(32, 17), blk, 0, stream>>>(STc, STb);
  k_chunkD<<<dim3(1024), blk, 0, stream>>>(Qb, Kb, Vtb, STb, attnb);
  // output projection (M=4096, N=1024, K=1024), 256x64 8-phase, grid=256
  k_gemm256_out<<<dim3(16, 16), dim3(512), 0, stream>>>(attnb, wout, out_b, out);
}